// Round 15
// baseline (227.635 us; speedup 1.0000x reference)
//
#include <hip/hip_runtime.h>
#include <hip/hip_bf16.h>
#include <hip/hip_fp16.h>
#include <math.h>

#define NN 20000
#define EE 320000
#define GG 64
#define IND 256
#define HD 256
#define CC 2

#define HRB 32           // edge ranges for histogram/fill
#define EPB (EE/HRB)     // 10000 edges per range
#define NQ  (NN/4)       // node quarter (LDS 20KB -> 8 blocks/CU)

typedef __hip_bfloat16 bf16;
typedef __attribute__((ext_vector_type(8))) short short8;
typedef __attribute__((ext_vector_type(4))) float f32x4;

__device__ __forceinline__ float b2f(bf16 x){ return __bfloat162float(x); }
__device__ __forceinline__ float bits2f(unsigned short b){
    union{ float f; unsigned u; } v; v.u = ((unsigned)b) << 16; return v.f;
}
__device__ __forceinline__ short f2bs(float x){
    union{ bf16 b; short s; } u; u.b = __float2bfloat16(x); return u.s;
}
// float load by code: 0=fp32, 1=bf16, 2=fp16
__device__ __forceinline__ float ldf3(const void* p, size_t i, int c){
    if (c == 1) return b2f(((const bf16*)p)[i]);
    if (c == 2) return __half2float(((const __half*)p)[i]);
    return ((const float*)p)[i];
}
__device__ __forceinline__ int idec(const void* p, int i, int c){
    if (c == 1) return (int)(((const long long*)p)[i]);
    if (c == 2) return (int)(((const float*)p)[i]);
    if (c == 3) return (int)__half2float(((const __half*)p)[i]);
    return ((const int*)p)[i];
}
// wave-parallel (64-lane) float-dtype detect; call with full wave, t = lane.
__device__ __forceinline__ int wdetect_wave(const unsigned short* p, int t){
    unsigned u = p[2*t];
    int e8 = (u >> 7) & 0xFF;
    int e5 = (u >> 10) & 0x1F;
    int nz = __popcll(__ballot(u != 0));
    int cb = __popcll(__ballot(e8 >= 100 && e8 <= 141));
    int cf = __popcll(__ballot(e5 >= 4 && e5 <= 22));
    return (nz < 8) ? 0 : (cb >= 60) ? 1 : ((cf >= 60) ? 2 : 0);
}

// ---- detection (lane-parallel) + W transpose + hg zeroing ----
#define ZBLK 8
#define DETB (9 + IND)
__global__ __launch_bounds__(256) void k_detect(const void* src, const void* dst,
                         const void* gid,
                         const unsigned short* h, const unsigned short* Wc,
                         const unsigned short* wg, const unsigned short* W1,
                         const unsigned short* W2, const unsigned short* bc,
                         int* icode, int* dcode, int* zero_base,
                         bf16* __restrict__ Wb){
    int blk = blockIdx.x;
    int t = threadIdx.x;
    if (blk < 3){
        if (t >= 64) return;
        const void* buf = (blk == 0) ? src : (blk == 1) ? dst : gid;
        int n     = (blk == 2) ? NN : EE;
        int bound = (blk == 2) ? GG : NN;
        long long v64 = ((const long long*)buf)[n/8 + t];
        unsigned long long bad64 = __ballot(v64 < 0 || v64 >= (long long)bound);
        int v32 = ((const int*)buf)[n/4 + t];
        unsigned long long bad32 = __ballot(v32 < 0 || v32 >= bound);
        float f32v = __uint_as_float(((const unsigned*)buf)[n/4 + t]);
        unsigned long long badf32 = __ballot(!(f32v >= 0.f && f32v < (float)bound));
        float f16v = __half2float(((const __half*)buf)[n/2 + t]);
        unsigned long long badf16 = __ballot(!(f16v >= 0.f && f16v < (float)bound));
        if (t == 0)
            icode[blk] = (bad64 == 0ull) ? 1 : ((bad32 == 0ull) ? 0 :
                         ((badf32 == 0ull) ? 2 : ((badf16 == 0ull) ? 3 : 0)));
    } else if (blk < 9){
        if (t >= 64) return;
        int b = blk - 3;
        const unsigned short* p = b==0?h:b==1?Wc:b==2?wg:b==3?W1:b==4?W2:bc;
        int code = wdetect_wave(p, t);
        if (t == 0) dcode[b] = code;
    } else if (blk < DETB){
        // W_conv[IN][HD] -> Wb[n][k] bf16 (fragment-friendly transpose)
        int k = blk - 9;
        __shared__ int scode;
        if (t < 64){
            int code = wdetect_wave(Wc, t);
            if (t == 0) scode = code;
        }
        __syncthreads();
        int c = scode;
        Wb[(size_t)t*IND + k] = __float2bfloat16(ldf3(Wc, (size_t)k*HD + t, c));
    } else {
        int idx = (blk - DETB)*256 + t;
        const int total = GG*HD;   // hg only (all other buffers written in full)
        for (int i = idx; i < total; i += ZBLK*256) zero_base[i] = 0;
    }
}

// fused MFMA GEMM + LDS-privatized degree histograms (NO global atomics).
// blocks [0, GEMMB): hn[32 rows] = h @ W_conv, coalesced LDS-staged stores.
// blocks [GEMMB, GEMMB+HRB*8): histogram by node-QUARTER (20KB LDS,
//   8 blocks/CU): hb=(blk-GEMMB): hr=hb>>3, role=(hb>>2)&1, q4=hb&3.
// Hist blocks overlap with the GEMM's memory phase (R10/R12-proven).
#define GEMMB (NN/32)
__global__ __launch_bounds__(256) void k_prepgemm(const void* __restrict__ h,
                                                  const bf16* __restrict__ Wb,
                                                  const void* __restrict__ src_r,
                                                  const void* __restrict__ dst_r,
                                                  const int* __restrict__ icode,
                                                  const int* __restrict__ dcode,
                                                  int* __restrict__ pout,
                                                  int* __restrict__ pin,
                                                  bf16* __restrict__ hn){
    __shared__ int shm[NQ];    // 20KB: histogram, or (aliased) epilogue tile
    int blk = blockIdx.x;
    int tid = threadIdx.x;
    if (blk >= GEMMB){
        int hb = blk - GEMMB;
        int hr = hb >> 3, role = (hb >> 2) & 1, q4 = hb & 3;
        for (int i = tid; i < NQ; i += 256) shm[i] = 0;
        __syncthreads();
        const void* arr = role ? dst_r : src_r;
        int code = icode[role];
        int base = hr*EPB;
        for (int e = base + tid; e < base + EPB; e += 256){
            int v = idec(arr, e, code);
            int vq = v - q4*NQ;
            if ((unsigned)vq < NQ) atomicAdd(&shm[vq], 1);
        }
        __syncthreads();
        int* dst_part = (role ? pin : pout) + (size_t)hr*NN + q4*NQ;
        for (int i = tid; i < NQ; i += 256) dst_part[i] = shm[i];
        return;
    }
    unsigned short* tile = (unsigned short*)shm;   // 32*260*2B = 16.6KB <= 20KB
    int fh = dcode[0];
    int wave = tid >> 6, lane = tid & 63;
    int q = lane >> 4, mr = lane & 15;
    int row0 = blk * 32;
    int ncol0 = wave * 64;
    f32x4 acc[2][4] = {};
    const float* hf = (const float*)h;
    #pragma unroll
    for (int k0 = 0; k0 < IND; k0 += 32){
        short8 a[2], b[4];
        if (fh == 0){
            #pragma unroll
            for (int mi = 0; mi < 2; mi++){
                int r = row0 + mi*16 + mr;
                const float4* p = (const float4*)(hf + (size_t)r*IND + k0 + q*8);
                float4 v0 = p[0], v1 = p[1];
                a[mi][0] = f2bs(v0.x); a[mi][1] = f2bs(v0.y);
                a[mi][2] = f2bs(v0.z); a[mi][3] = f2bs(v0.w);
                a[mi][4] = f2bs(v1.x); a[mi][5] = f2bs(v1.y);
                a[mi][6] = f2bs(v1.z); a[mi][7] = f2bs(v1.w);
            }
        } else {
            #pragma unroll
            for (int mi = 0; mi < 2; mi++){
                int r = row0 + mi*16 + mr;
                #pragma unroll
                for (int j = 0; j < 8; j++)
                    a[mi][j] = f2bs(ldf3(h, (size_t)r*IND + k0 + q*8 + j, fh));
            }
        }
        #pragma unroll
        for (int ni = 0; ni < 4; ni++)
            b[ni] = *reinterpret_cast<const short8*>(
                        Wb + (size_t)(ncol0 + ni*16 + mr)*IND + k0 + q*8);
        #pragma unroll
        for (int mi = 0; mi < 2; mi++)
            #pragma unroll
            for (int ni = 0; ni < 4; ni++)
                acc[mi][ni] = __builtin_amdgcn_mfma_f32_16x16x32_bf16(
                                  a[mi], b[ni], acc[mi][ni], 0, 0, 0);
    }
    #pragma unroll
    for (int mi = 0; mi < 2; mi++){
        int rowb = mi*16 + q*4;
        #pragma unroll
        for (int r = 0; r < 4; r++){
            int row = rowb + r;
            #pragma unroll
            for (int ni = 0; ni < 4; ni++)
                tile[row*260 + ncol0 + ni*16 + mr] =
                    (unsigned short)f2bs(acc[mi][ni][r]);
        }
    }
    __syncthreads();
    #pragma unroll
    for (int p = 0; p < 4; p++){
        int s = p*256 + tid;
        int row = s >> 5;
        int c8 = (s & 31) * 8;
        short8 v = *reinterpret_cast<const short8*>(&tile[row*260 + c8]);
        *reinterpret_cast<short8*>(hn + (size_t)(row0 + row)*HD + c8) = v;
    }
}

// per-node reduce: sum pout -> rs_o; exclusive-prefix pin in place ->
// per-range row offsets; totals -> cnt_in, rs_i; decode gid.
__global__ __launch_bounds__(256) void k_red(const void* __restrict__ gid_r,
                                             const int* __restrict__ icode,
                                             int* __restrict__ pout,
                                             int* __restrict__ pin,
                                             float* __restrict__ rs_o,
                                             float* __restrict__ rs_i,
                                             int* __restrict__ cnt_in,
                                             int* __restrict__ gid_i){
    int n = blockIdx.x*256 + threadIdx.x;
    if (n >= NN) return;
    int so = 0;
    #pragma unroll 8
    for (int hr = 0; hr < HRB; hr++) so += pout[(size_t)hr*NN + n];
    rs_o[n] = rsqrtf(fmaxf((float)so, 1.f));
    int pre = 0;
    #pragma unroll 8
    for (int hr = 0; hr < HRB; hr++){
        int v = pin[(size_t)hr*NN + n];
        pin[(size_t)hr*NN + n] = pre;
        pre += v;
    }
    cnt_in[n] = pre;
    rs_i[n] = rsqrtf(fmaxf((float)pre, 1.f));
    gid_i[n] = idec(gid_r, n, icode[2]);
}

// single-block (1024 threads): prefix scan of cnt_in -> rowst + graph ranges
__global__ __launch_bounds__(1024) void k_scan(const int* __restrict__ cnt_in,
                                               const int* __restrict__ gid,
                                               int* __restrict__ row_start,
                                               int* gstart, int* gend){
    int t = threadIdx.x;
    __shared__ int part[1024];
    const int per = (NN + 1023)/1024;
    int lo = t*per, hi = min(lo+per, NN);
    int s = 0;
    for (int i = lo; i < hi; i++) s += cnt_in[i];
    part[t] = s; __syncthreads();
    for (int off = 1; off < 1024; off <<= 1){
        int v = (t >= off) ? part[t-off] : 0;
        __syncthreads();
        part[t] += v;
        __syncthreads();
    }
    int base = part[t] - s;
    for (int i = lo; i < hi; i++){ row_start[i] = base; base += cnt_in[i]; }
    if (t == 1023) row_start[NN] = part[1023];
    __shared__ int ls[GG+1];
    if (t <= GG){
        int a = 0, b = NN;
        while (a < b){
            int mid = (a + b) >> 1;
            if (gid[mid] < t) a = mid + 1; else b = mid;
        }
        ls[t] = a;
    }
    __syncthreads();
    if (t < GG){ gstart[t] = ls[t]; gend[t] = ls[t+1]; }
}

// atomic-free CSR fill by node-quarter: blk -> (hr = blk>>2, q4 = blk&3).
// 128 blocks (2x the half-based parallelism), 20KB LDS local-rank array.
// slot = rowst[d] + pin_prefix[hr][d] + LDS local rank (unique per (hr,d)).
__global__ __launch_bounds__(256) void k_fill(const void* src_r, const void* dst_r,
                       const int* __restrict__ icode,
                       const int* __restrict__ row_start,
                       const int* __restrict__ pin,
                       int* __restrict__ csr_src){
    __shared__ int lr[NQ];
    int blk = blockIdx.x, t = threadIdx.x;
    int hr = blk >> 2, q4 = blk & 3;
    for (int i = t; i < NQ; i += 256) lr[i] = 0;
    __syncthreads();
    int c0 = icode[0], c1 = icode[1];
    int base = hr*EPB;
    const int* pre = pin + (size_t)hr*NN;
    for (int e = base + t; e < base + EPB; e += 256){
        int s = idec(src_r, e, c0);
        int d = idec(dst_r, e, c1);
        if ((unsigned)s >= NN || (unsigned)d >= NN) continue;
        int dh = d - q4*NQ;
        if ((unsigned)dh < NQ){
            int r = atomicAdd(&lr[dh], 1);
            csr_src[row_start[d] + pre[d] + r] = s;
        }
    }
}

// fused gather + epilogue: one wave per dst node.
// Half-wave pairing: lanes l and l+32 read DIFFERENT edges with 16B short8
// loads. rs_out[src] applied per-edge via fma.
__global__ __launch_bounds__(256) void k_gather(const bf16* __restrict__ hn,
                                                const float* __restrict__ rs_out,
                                                const float* __restrict__ rs_in,
                                                const int* __restrict__ row_start,
                                                const int* __restrict__ csr_src,
                                                const void* __restrict__ b_conv,
                                                const void* __restrict__ w_gate,
                                                const void* __restrict__ b_gate,
                                                const int* __restrict__ dcode,
                                                float* __restrict__ hr,
                                                float* __restrict__ gate){
    int wave = threadIdx.x >> 6, lane = threadIdx.x & 63;
    int n = blockIdx.x*4 + wave;
    if (n >= NN) return;
    int lo = row_start[n], hi = row_start[n+1];
    int half = lane >> 5, l2 = lane & 31;
    float a0=0.f,a1=0.f,a2=0.f,a3=0.f,a4=0.f,a5=0.f,a6=0.f,a7=0.f;
    int j = lo;
    for (; j + 8 <= hi; j += 8){
        int sA = csr_src[j+0+half], sB = csr_src[j+2+half];
        int sC = csr_src[j+4+half], sD = csr_src[j+6+half];
        float rA = rs_out[sA], rB = rs_out[sB], rC = rs_out[sC], rD = rs_out[sD];
        short8 uA = *reinterpret_cast<const short8*>(hn + (size_t)sA*HD + l2*8);
        short8 uB = *reinterpret_cast<const short8*>(hn + (size_t)sB*HD + l2*8);
        short8 uC = *reinterpret_cast<const short8*>(hn + (size_t)sC*HD + l2*8);
        short8 uD = *reinterpret_cast<const short8*>(hn + (size_t)sD*HD + l2*8);
        a0 = fmaf(rA, bits2f((unsigned short)uA[0]),
             fmaf(rB, bits2f((unsigned short)uB[0]),
             fmaf(rC, bits2f((unsigned short)uC[0]),
             fmaf(rD, bits2f((unsigned short)uD[0]), a0))));
        a1 = fmaf(rA, bits2f((unsigned short)uA[1]),
             fmaf(rB, bits2f((unsigned short)uB[1]),
             fmaf(rC, bits2f((unsigned short)uC[1]),
             fmaf(rD, bits2f((unsigned short)uD[1]), a1))));
        a2 = fmaf(rA, bits2f((unsigned short)uA[2]),
             fmaf(rB, bits2f((unsigned short)uB[2]),
             fmaf(rC, bits2f((unsigned short)uC[2]),
             fmaf(rD, bits2f((unsigned short)uD[2]), a2))));
        a3 = fmaf(rA, bits2f((unsigned short)uA[3]),
             fmaf(rB, bits2f((unsigned short)uB[3]),
             fmaf(rC, bits2f((unsigned short)uC[3]),
             fmaf(rD, bits2f((unsigned short)uD[3]), a3))));
        a4 = fmaf(rA, bits2f((unsigned short)uA[4]),
             fmaf(rB, bits2f((unsigned short)uB[4]),
             fmaf(rC, bits2f((unsigned short)uC[4]),
             fmaf(rD, bits2f((unsigned short)uD[4]), a4))));
        a5 = fmaf(rA, bits2f((unsigned short)uA[5]),
             fmaf(rB, bits2f((unsigned short)uB[5]),
             fmaf(rC, bits2f((unsigned short)uC[5]),
             fmaf(rD, bits2f((unsigned short)uD[5]), a5))));
        a6 = fmaf(rA, bits2f((unsigned short)uA[6]),
             fmaf(rB, bits2f((unsigned short)uB[6]),
             fmaf(rC, bits2f((unsigned short)uC[6]),
             fmaf(rD, bits2f((unsigned short)uD[6]), a6))));
        a7 = fmaf(rA, bits2f((unsigned short)uA[7]),
             fmaf(rB, bits2f((unsigned short)uB[7]),
             fmaf(rC, bits2f((unsigned short)uC[7]),
             fmaf(rD, bits2f((unsigned short)uD[7]), a7))));
    }
    for (; j + 2 <= hi; j += 2){
        int s = csr_src[j+half];
        float r = rs_out[s];
        short8 u = *reinterpret_cast<const short8*>(hn + (size_t)s*HD + l2*8);
        a0 = fmaf(r, bits2f((unsigned short)u[0]), a0);
        a1 = fmaf(r, bits2f((unsigned short)u[1]), a1);
        a2 = fmaf(r, bits2f((unsigned short)u[2]), a2);
        a3 = fmaf(r, bits2f((unsigned short)u[3]), a3);
        a4 = fmaf(r, bits2f((unsigned short)u[4]), a4);
        a5 = fmaf(r, bits2f((unsigned short)u[5]), a5);
        a6 = fmaf(r, bits2f((unsigned short)u[6]), a6);
        a7 = fmaf(r, bits2f((unsigned short)u[7]), a7);
    }
    if (j < hi && half == 0){
        int s = csr_src[j];
        float r = rs_out[s];
        short8 u = *reinterpret_cast<const short8*>(hn + (size_t)s*HD + l2*8);
        a0 = fmaf(r, bits2f((unsigned short)u[0]), a0);
        a1 = fmaf(r, bits2f((unsigned short)u[1]), a1);
        a2 = fmaf(r, bits2f((unsigned short)u[2]), a2);
        a3 = fmaf(r, bits2f((unsigned short)u[3]), a3);
        a4 = fmaf(r, bits2f((unsigned short)u[4]), a4);
        a5 = fmaf(r, bits2f((unsigned short)u[5]), a5);
        a6 = fmaf(r, bits2f((unsigned short)u[6]), a6);
        a7 = fmaf(r, bits2f((unsigned short)u[7]), a7);
    }
    // exchange: send the 4 channels the partner owns, receive my 4
    float send0 = half ? a0 : a4;
    float send1 = half ? a1 : a5;
    float send2 = half ? a2 : a6;
    float send3 = half ? a3 : a7;
    float recv0 = __shfl_xor(send0, 32);
    float recv1 = __shfl_xor(send1, 32);
    float recv2 = __shfl_xor(send2, 32);
    float recv3 = __shfl_xor(send3, 32);
    float tot0 = (half ? a4 : a0) + recv0;
    float tot1 = (half ? a5 : a1) + recv1;
    float tot2 = (half ? a6 : a2) + recv2;
    float tot3 = (half ? a7 : a3) + recv3;
    int db = dcode[5], fg = dcode[2];
    float rsn = rs_in[n];
    int c = l2*8 + half*4;
    float v0 = fmaxf(fmaf(tot0, rsn, ldf3(b_conv, c+0, db)), 0.f);
    float v1 = fmaxf(fmaf(tot1, rsn, ldf3(b_conv, c+1, db)), 0.f);
    float v2 = fmaxf(fmaf(tot2, rsn, ldf3(b_conv, c+2, db)), 0.f);
    float v3 = fmaxf(fmaf(tot3, rsn, ldf3(b_conv, c+3, db)), 0.f);
    float4 fv; fv.x = v0; fv.y = v1; fv.z = v2; fv.w = v3;
    *(float4*)(hr + (size_t)n*HD + c) = fv;
    float g = v0*ldf3(w_gate, c+0, fg) + v1*ldf3(w_gate, c+1, fg)
            + v2*ldf3(w_gate, c+2, fg) + v3*ldf3(w_gate, c+3, fg);
    #pragma unroll
    for (int off = 32; off; off >>= 1) g += __shfl_down(g, off);
    if (lane == 0) gate[n] = g + ldf3(b_gate, 0, db);
}

// fused softmax + attention pool: 8 parts per graph (512 blocks), NO fences.
__global__ __launch_bounds__(256) void k_softhg(const float* __restrict__ gate,
                                                const float* __restrict__ hr,
                                                const int* __restrict__ gstart,
                                                const int* __restrict__ gend,
                                                float* __restrict__ hg,
                                                float* __restrict__ out_att){
    int g = blockIdx.x >> 3, part = blockIdx.x & 7;
    int t = threadIdx.x, lane = t & 63, wid = t >> 6;
    int lo = gstart[g], hi = gend[g], len = hi - lo;
    if (len <= 0) return;
    __shared__ float red[4];
    // --- segment max ---
    float m = -INFINITY;
    for (int n = lo + t; n < hi; n += 256) m = fmaxf(m, gate[n]);
    #pragma unroll
    for (int off = 32; off; off >>= 1) m = fmaxf(m, __shfl_xor(m, off));
    if (lane == 0) red[wid] = m;
    __syncthreads();
    m = fmaxf(fmaxf(red[0], red[1]), fmaxf(red[2], red[3]));
    __syncthreads();
    // --- segment sum of exp ---
    float s = 0.f;
    for (int n = lo + t; n < hi; n += 256) s += expf(gate[n] - m);
    #pragma unroll
    for (int off = 32; off; off >>= 1) s += __shfl_xor(s, off);
    if (lane == 0) red[wid] = s;
    __syncthreads();
    s = red[0] + red[1] + red[2] + red[3];
    float inv = 1.f / s;
    // --- this part's node slice ---
    int chunk = (len + 7) >> 3;
    int plo = lo + part*chunk, phi = min(plo + chunk, hi);
    if (plo >= phi) return;
    for (int n = plo + t; n < phi; n += 256)
        out_att[n] = expf(gate[n] - m) * inv;
    float a0 = 0.f, a1 = 0.f, a2 = 0.f, a3 = 0.f;
    int r = plo;
    for (; r + 4 <= phi; r += 4){
        float w0 = expf(gate[r+0] - m) * inv;
        float w1 = expf(gate[r+1] - m) * inv;
        float w2 = expf(gate[r+2] - m) * inv;
        float w3 = expf(gate[r+3] - m) * inv;
        a0 = fmaf(w0, hr[(size_t)(r+0)*HD + t], a0);
        a1 = fmaf(w1, hr[(size_t)(r+1)*HD + t], a1);
        a2 = fmaf(w2, hr[(size_t)(r+2)*HD + t], a2);
        a3 = fmaf(w3, hr[(size_t)(r+3)*HD + t], a3);
    }
    for (; r < phi; r++)
        a0 = fmaf(expf(gate[r] - m) * inv, hr[(size_t)r*HD + t], a0);
    atomicAdd(&hg[g*HD + t], (a0 + a1) + (a2 + a3));
}

// classifier: one block per graph (round-0 proven)
__global__ __launch_bounds__(256) void k_cls(const float* __restrict__ hg,
                                             const void* __restrict__ W1,
                                             const void* __restrict__ b1,
                                             const void* __restrict__ W2,
                                             const void* __restrict__ b2,
                                             const int* __restrict__ dcode,
                                             float* __restrict__ out0,
                                             float* __restrict__ out_hg){
    int f1 = dcode[3], f2 = dcode[4], db = dcode[5];
    int g = blockIdx.x, tid = threadIdx.x;
    __shared__ float hs[256];
    float hv = hg[g*HD + tid];
    hs[tid] = hv;
    out_hg[g*HD + tid] = hv;
    __syncthreads();
    float acc = ldf3(b1, tid, db);
    if (f1 == 1){
        const bf16* w = (const bf16*)W1;
        for (int k = 0; k < HD; k++) acc += hs[k]*b2f(w[(size_t)k*HD + tid]);
    } else if (f1 == 2){
        const __half* w = (const __half*)W1;
        for (int k = 0; k < HD; k++) acc += hs[k]*__half2float(w[(size_t)k*HD + tid]);
    } else {
        const float* w = (const float*)W1;
        for (int k = 0; k < HD; k++) acc += hs[k]*w[(size_t)k*HD + tid];
    }
    float p0 = acc * ldf3(W2, tid*CC + 0, f2);
    float p1 = acc * ldf3(W2, tid*CC + 1, f2);
    __shared__ float r0[256], r1[256];
    r0[tid] = p0; r1[tid] = p1; __syncthreads();
    for (int s = 128; s; s >>= 1){
        if (tid < s){ r0[tid] += r0[tid+s]; r1[tid] += r1[tid+s]; }
        __syncthreads();
    }
    if (tid == 0){
        out0[g*CC+0] = 1.f/(1.f + expf(-(r0[0] + ldf3(b2, 0, db))));
        out0[g*CC+1] = 1.f/(1.f + expf(-(r1[0] + ldf3(b2, 1, db))));
    }
}

extern "C" void kernel_launch(void* const* d_in, const int* in_sizes, int n_in,
                              void* d_out, int out_size, void* d_ws, size_t ws_size,
                              hipStream_t stream) {
    const void* h      = d_in[0];
    const void* src_r  = d_in[1];
    const void* dst_r  = d_in[2];
    const void* gid_r  = d_in[3];
    const void* W_conv = d_in[4];
    const void* b_conv = d_in[5];
    const void* w_gate = d_in[6];
    const void* b_gate = d_in[7];
    const void* W1     = d_in[8];
    const void* b1     = d_in[9];
    const void* W2     = d_in[10];
    const void* b2     = d_in[11];

    float* out     = (float*)d_out;      // fp32 output (established R10)
    float* out0    = out;                // [G,C]
    float* out_att = out + GG*CC;        // [N]
    float* out_hg  = out + GG*CC + NN;   // [G,H]

    char* w = (char*)d_ws;
    float* hr   = (float*)w;  w += (size_t)NN*HD*sizeof(float);
    bf16*  hn   = (bf16*)w;   w += (size_t)NN*HD*sizeof(bf16);
    bf16*  Wb   = (bf16*)w;   w += (size_t)IND*HD*sizeof(bf16);
    float* rs_o = (float*)w;  w += (size_t)NN*sizeof(float);
    float* rs_i = (float*)w;  w += (size_t)NN*sizeof(float);
    float* gate = (float*)w;  w += (size_t)NN*sizeof(float);
    int* gstart = (int*)w;    w += GG*sizeof(int);
    int* gend   = (int*)w;    w += GG*sizeof(int);
    int* dcode  = (int*)w;    w += 8*sizeof(int);
    int* icode  = (int*)w;    w += 8*sizeof(int);
    int* gid_i  = (int*)w;    w += (size_t)NN*sizeof(int);
    int* cnt_in = (int*)w;    w += (size_t)NN*sizeof(int);
    float* hg   = (float*)w;  w += (size_t)GG*HD*sizeof(float);   // zeroed
    int* rowst  = (int*)w;    w += (size_t)(NN+1)*sizeof(int);
    int* csr    = (int*)w;    w += (size_t)EE*sizeof(int);
    int* pout   = (int*)w;    w += (size_t)HRB*NN*sizeof(int);
    int* pin    = (int*)w;    w += (size_t)HRB*NN*sizeof(int);

    // detection + W transpose + hg zeroing
    k_detect<<<DETB + ZBLK, 256, 0, stream>>>(src_r, dst_r, gid_r,
                                     (const unsigned short*)h, (const unsigned short*)W_conv,
                                     (const unsigned short*)w_gate, (const unsigned short*)W1,
                                     (const unsigned short*)W2, (const unsigned short*)b_conv,
                                     icode, dcode, (int*)hg, Wb);

    // GEMM (coalesced epilogue) + LDS histograms (quarter-parallel), 1 launch
    k_prepgemm<<<GEMMB + HRB*8, 256, 0, stream>>>(h, Wb, src_r, dst_r,
                                                  icode, dcode, pout, pin, hn);

    k_red<<<(NN+255)/256, 256, 0, stream>>>(gid_r, icode, pout, pin,
                                            rs_o, rs_i, cnt_in, gid_i);

    k_scan<<<1, 1024, 0, stream>>>(cnt_in, gid_i, rowst, gstart, gend);

    k_fill<<<HRB*4, 256, 0, stream>>>(src_r, dst_r, icode, rowst, pin, csr);

    k_gather<<<(NN+3)/4, 256, 0, stream>>>(hn, rs_o, rs_i, rowst, csr,
                                           b_conv, w_gate, b_gate, dcode, hr, gate);

    k_softhg<<<GG*8, 256, 0, stream>>>(gate, hr, gstart, gend, hg, out_att);

    k_cls<<<GG, 256, 0, stream>>>(hg, W1, b1, W2, b2, dcode, out0, out_hg);
}

// Round 16
// 223.326 us; speedup vs baseline: 1.0193x; 1.0193x over previous
//
#include <hip/hip_runtime.h>
#include <hip/hip_bf16.h>
#include <hip/hip_fp16.h>
#include <math.h>

#define NN 20000
#define EE 320000
#define GG 64
#define IND 256
#define HD 256
#define CC 2

#define HRB 32           // edge ranges for histogram/fill
#define EPB (EE/HRB)     // 10000 edges per range
#define NH  (NN/2)       // node half size (LDS histogram fits 40KB)

typedef __hip_bfloat16 bf16;
typedef __attribute__((ext_vector_type(8))) short short8;
typedef __attribute__((ext_vector_type(4))) float f32x4;

__device__ __forceinline__ float b2f(bf16 x){ return __bfloat162float(x); }
__device__ __forceinline__ float bits2f(unsigned short b){
    union{ float f; unsigned u; } v; v.u = ((unsigned)b) << 16; return v.f;
}
__device__ __forceinline__ short f2bs(float x){
    union{ bf16 b; short s; } u; u.b = __float2bfloat16(x); return u.s;
}
// float load by code: 0=fp32, 1=bf16, 2=fp16
__device__ __forceinline__ float ldf3(const void* p, size_t i, int c){
    if (c == 1) return b2f(((const bf16*)p)[i]);
    if (c == 2) return __half2float(((const __half*)p)[i]);
    return ((const float*)p)[i];
}
__device__ __forceinline__ int idec(const void* p, int i, int c){
    if (c == 1) return (int)(((const long long*)p)[i]);
    if (c == 2) return (int)(((const float*)p)[i]);
    if (c == 3) return (int)__half2float(((const __half*)p)[i]);
    return ((const int*)p)[i];
}
// wave-parallel (64-lane) float-dtype detect; call with full wave, t = lane.
__device__ __forceinline__ int wdetect_wave(const unsigned short* p, int t){
    unsigned u = p[2*t];
    int e8 = (u >> 7) & 0xFF;
    int e5 = (u >> 10) & 0x1F;
    int nz = __popcll(__ballot(u != 0));
    int cb = __popcll(__ballot(e8 >= 100 && e8 <= 141));
    int cf = __popcll(__ballot(e5 >= 4 && e5 <= 22));
    return (nz < 8) ? 0 : (cb >= 60) ? 1 : ((cf >= 60) ? 2 : 0);
}

// ---- detection (lane-parallel) + W transpose + hg zeroing ----
#define ZBLK 8
#define DETB (9 + IND)
__global__ __launch_bounds__(256) void k_detect(const void* src, const void* dst,
                         const void* gid,
                         const unsigned short* h, const unsigned short* Wc,
                         const unsigned short* wg, const unsigned short* W1,
                         const unsigned short* W2, const unsigned short* bc,
                         int* icode, int* dcode, int* zero_base,
                         bf16* __restrict__ Wb){
    int blk = blockIdx.x;
    int t = threadIdx.x;
    if (blk < 3){
        if (t >= 64) return;
        const void* buf = (blk == 0) ? src : (blk == 1) ? dst : gid;
        int n     = (blk == 2) ? NN : EE;
        int bound = (blk == 2) ? GG : NN;
        long long v64 = ((const long long*)buf)[n/8 + t];
        unsigned long long bad64 = __ballot(v64 < 0 || v64 >= (long long)bound);
        int v32 = ((const int*)buf)[n/4 + t];
        unsigned long long bad32 = __ballot(v32 < 0 || v32 >= bound);
        float f32v = __uint_as_float(((const unsigned*)buf)[n/4 + t]);
        unsigned long long badf32 = __ballot(!(f32v >= 0.f && f32v < (float)bound));
        float f16v = __half2float(((const __half*)buf)[n/2 + t]);
        unsigned long long badf16 = __ballot(!(f16v >= 0.f && f16v < (float)bound));
        if (t == 0)
            icode[blk] = (bad64 == 0ull) ? 1 : ((bad32 == 0ull) ? 0 :
                         ((badf32 == 0ull) ? 2 : ((badf16 == 0ull) ? 3 : 0)));
    } else if (blk < 9){
        if (t >= 64) return;
        int b = blk - 3;
        const unsigned short* p = b==0?h:b==1?Wc:b==2?wg:b==3?W1:b==4?W2:bc;
        int code = wdetect_wave(p, t);
        if (t == 0) dcode[b] = code;
    } else if (blk < DETB){
        // W_conv[IN][HD] -> Wb[n][k] bf16 (fragment-friendly transpose)
        int k = blk - 9;
        __shared__ int scode;
        if (t < 64){
            int code = wdetect_wave(Wc, t);
            if (t == 0) scode = code;
        }
        __syncthreads();
        int c = scode;
        Wb[(size_t)t*IND + k] = __float2bfloat16(ldf3(Wc, (size_t)k*HD + t, c));
    } else {
        int idx = (blk - DETB)*256 + t;
        const int total = GG*HD;   // hg only (all other buffers written in full)
        for (int i = idx; i < total; i += ZBLK*256) zero_base[i] = 0;
    }
}

// fused MFMA GEMM + LDS-privatized degree histograms (NO global atomics).
// blocks [0, GEMMB): hn[32 rows] = h @ W_conv, coalesced LDS-staged stores.
// blocks [GEMMB, GEMMB+HRB*4): histogram. hb=(blk-GEMMB): hr=hb>>2,
//   role=(hb>>1)&1 (0:src->pout, 1:dst->pin), half=hb&1 (node range half).
// Hist blocks overlap with the GEMM's memory phase (R10/R12-proven; moving
// them earlier (R11), into a cooperative mid-kernel (R13), or splitting by
// node-quarter (R15) all regressed).
#define GEMMB (NN/32)
__global__ __launch_bounds__(256) void k_prepgemm(const void* __restrict__ h,
                                                  const bf16* __restrict__ Wb,
                                                  const void* __restrict__ src_r,
                                                  const void* __restrict__ dst_r,
                                                  const int* __restrict__ icode,
                                                  const int* __restrict__ dcode,
                                                  int* __restrict__ pout,
                                                  int* __restrict__ pin,
                                                  bf16* __restrict__ hn){
    __shared__ int shm[NH];    // 40KB: histogram, or (aliased) epilogue tile
    int blk = blockIdx.x;
    int tid = threadIdx.x;
    if (blk >= GEMMB){
        int hb = blk - GEMMB;
        int hr = hb >> 2, role = (hb >> 1) & 1, half = hb & 1;
        for (int i = tid; i < NH; i += 256) shm[i] = 0;
        __syncthreads();
        const void* arr = role ? dst_r : src_r;
        int code = icode[role];
        int base = hr*EPB;
        for (int e = base + tid; e < base + EPB; e += 256){
            int v = idec(arr, e, code);
            int vh = v - half*NH;
            if ((unsigned)vh < NH) atomicAdd(&shm[vh], 1);
        }
        __syncthreads();
        int* dst_part = (role ? pin : pout) + (size_t)hr*NN + half*NH;
        for (int i = tid; i < NH; i += 256) dst_part[i] = shm[i];
        return;
    }
    unsigned short* tile = (unsigned short*)shm;   // 32*260*2B = 16.6KB <= 40KB
    int fh = dcode[0];
    int wave = tid >> 6, lane = tid & 63;
    int q = lane >> 4, mr = lane & 15;
    int row0 = blk * 32;
    int ncol0 = wave * 64;
    f32x4 acc[2][4] = {};
    const float* hf = (const float*)h;
    #pragma unroll
    for (int k0 = 0; k0 < IND; k0 += 32){
        short8 a[2], b[4];
        if (fh == 0){
            #pragma unroll
            for (int mi = 0; mi < 2; mi++){
                int r = row0 + mi*16 + mr;
                const float4* p = (const float4*)(hf + (size_t)r*IND + k0 + q*8);
                float4 v0 = p[0], v1 = p[1];
                a[mi][0] = f2bs(v0.x); a[mi][1] = f2bs(v0.y);
                a[mi][2] = f2bs(v0.z); a[mi][3] = f2bs(v0.w);
                a[mi][4] = f2bs(v1.x); a[mi][5] = f2bs(v1.y);
                a[mi][6] = f2bs(v1.z); a[mi][7] = f2bs(v1.w);
            }
        } else {
            #pragma unroll
            for (int mi = 0; mi < 2; mi++){
                int r = row0 + mi*16 + mr;
                #pragma unroll
                for (int j = 0; j < 8; j++)
                    a[mi][j] = f2bs(ldf3(h, (size_t)r*IND + k0 + q*8 + j, fh));
            }
        }
        #pragma unroll
        for (int ni = 0; ni < 4; ni++)
            b[ni] = *reinterpret_cast<const short8*>(
                        Wb + (size_t)(ncol0 + ni*16 + mr)*IND + k0 + q*8);
        #pragma unroll
        for (int mi = 0; mi < 2; mi++)
            #pragma unroll
            for (int ni = 0; ni < 4; ni++)
                acc[mi][ni] = __builtin_amdgcn_mfma_f32_16x16x32_bf16(
                                  a[mi], b[ni], acc[mi][ni], 0, 0, 0);
    }
    #pragma unroll
    for (int mi = 0; mi < 2; mi++){
        int rowb = mi*16 + q*4;
        #pragma unroll
        for (int r = 0; r < 4; r++){
            int row = rowb + r;
            #pragma unroll
            for (int ni = 0; ni < 4; ni++)
                tile[row*260 + ncol0 + ni*16 + mr] =
                    (unsigned short)f2bs(acc[mi][ni][r]);
        }
    }
    __syncthreads();
    #pragma unroll
    for (int p = 0; p < 4; p++){
        int s = p*256 + tid;
        int row = s >> 5;
        int c8 = (s & 31) * 8;
        short8 v = *reinterpret_cast<const short8*>(&tile[row*260 + c8]);
        *reinterpret_cast<short8*>(hn + (size_t)(row0 + row)*HD + c8) = v;
    }
}

// per-node reduce: sum pout -> rs_o; exclusive-prefix pin in place ->
// per-range row offsets; totals -> cnt_in, rs_i; decode gid.
__global__ __launch_bounds__(256) void k_red(const void* __restrict__ gid_r,
                                             const int* __restrict__ icode,
                                             int* __restrict__ pout,
                                             int* __restrict__ pin,
                                             float* __restrict__ rs_o,
                                             float* __restrict__ rs_i,
                                             int* __restrict__ cnt_in,
                                             int* __restrict__ gid_i){
    int n = blockIdx.x*256 + threadIdx.x;
    if (n >= NN) return;
    int so = 0;
    #pragma unroll 8
    for (int hr = 0; hr < HRB; hr++) so += pout[(size_t)hr*NN + n];
    rs_o[n] = rsqrtf(fmaxf((float)so, 1.f));
    int pre = 0;
    #pragma unroll 8
    for (int hr = 0; hr < HRB; hr++){
        int v = pin[(size_t)hr*NN + n];
        pin[(size_t)hr*NN + n] = pre;
        pre += v;
    }
    cnt_in[n] = pre;
    rs_i[n] = rsqrtf(fmaxf((float)pre, 1.f));
    gid_i[n] = idec(gid_r, n, icode[2]);
}

// single-block (1024 threads): prefix scan of cnt_in -> rowst + graph ranges
__global__ __launch_bounds__(1024) void k_scan(const int* __restrict__ cnt_in,
                                               const int* __restrict__ gid,
                                               int* __restrict__ row_start,
                                               int* gstart, int* gend){
    int t = threadIdx.x;
    __shared__ int part[1024];
    const int per = (NN + 1023)/1024;
    int lo = t*per, hi = min(lo+per, NN);
    int s = 0;
    for (int i = lo; i < hi; i++) s += cnt_in[i];
    part[t] = s; __syncthreads();
    for (int off = 1; off < 1024; off <<= 1){
        int v = (t >= off) ? part[t-off] : 0;
        __syncthreads();
        part[t] += v;
        __syncthreads();
    }
    int base = part[t] - s;
    for (int i = lo; i < hi; i++){ row_start[i] = base; base += cnt_in[i]; }
    if (t == 1023) row_start[NN] = part[1023];
    __shared__ int ls[GG+1];
    if (t <= GG){
        int a = 0, b = NN;
        while (a < b){
            int mid = (a + b) >> 1;
            if (gid[mid] < t) a = mid + 1; else b = mid;
        }
        ls[t] = a;
    }
    __syncthreads();
    if (t < GG){ gstart[t] = ls[t]; gend[t] = ls[t+1]; }
}

// atomic-free CSR fill: blk -> (hr = blk>>1, half = blk&1). Re-streams range
// hr's edges; slot = rowst[d] + pin_prefix[hr][d] + LDS local rank.
__global__ __launch_bounds__(256) void k_fill(const void* src_r, const void* dst_r,
                       const int* __restrict__ icode,
                       const int* __restrict__ row_start,
                       const int* __restrict__ pin,
                       int* __restrict__ csr_src){
    __shared__ int lr[NH];
    int blk = blockIdx.x, t = threadIdx.x;
    int hr = blk >> 1, half = blk & 1;
    for (int i = t; i < NH; i += 256) lr[i] = 0;
    __syncthreads();
    int c0 = icode[0], c1 = icode[1];
    int base = hr*EPB;
    const int* pre = pin + (size_t)hr*NN;
    for (int e = base + t; e < base + EPB; e += 256){
        int s = idec(src_r, e, c0);
        int d = idec(dst_r, e, c1);
        if ((unsigned)s >= NN || (unsigned)d >= NN) continue;
        int dh = d - half*NH;
        if ((unsigned)dh < NH){
            int r = atomicAdd(&lr[dh], 1);
            csr_src[row_start[d] + pre[d] + r] = s;
        }
    }
}

// fused gather + epilogue: one wave per dst node.
// Half-wave pairing: lanes l and l+32 read DIFFERENT edges with 16B short8
// loads. rs_out[src] applied per-edge via fma.
__global__ __launch_bounds__(256) void k_gather(const bf16* __restrict__ hn,
                                                const float* __restrict__ rs_out,
                                                const float* __restrict__ rs_in,
                                                const int* __restrict__ row_start,
                                                const int* __restrict__ csr_src,
                                                const void* __restrict__ b_conv,
                                                const void* __restrict__ w_gate,
                                                const void* __restrict__ b_gate,
                                                const int* __restrict__ dcode,
                                                float* __restrict__ hr,
                                                float* __restrict__ gate){
    int wave = threadIdx.x >> 6, lane = threadIdx.x & 63;
    int n = blockIdx.x*4 + wave;
    if (n >= NN) return;
    int lo = row_start[n], hi = row_start[n+1];
    int half = lane >> 5, l2 = lane & 31;
    float a0=0.f,a1=0.f,a2=0.f,a3=0.f,a4=0.f,a5=0.f,a6=0.f,a7=0.f;
    int j = lo;
    for (; j + 8 <= hi; j += 8){
        int sA = csr_src[j+0+half], sB = csr_src[j+2+half];
        int sC = csr_src[j+4+half], sD = csr_src[j+6+half];
        float rA = rs_out[sA], rB = rs_out[sB], rC = rs_out[sC], rD = rs_out[sD];
        short8 uA = *reinterpret_cast<const short8*>(hn + (size_t)sA*HD + l2*8);
        short8 uB = *reinterpret_cast<const short8*>(hn + (size_t)sB*HD + l2*8);
        short8 uC = *reinterpret_cast<const short8*>(hn + (size_t)sC*HD + l2*8);
        short8 uD = *reinterpret_cast<const short8*>(hn + (size_t)sD*HD + l2*8);
        a0 = fmaf(rA, bits2f((unsigned short)uA[0]),
             fmaf(rB, bits2f((unsigned short)uB[0]),
             fmaf(rC, bits2f((unsigned short)uC[0]),
             fmaf(rD, bits2f((unsigned short)uD[0]), a0))));
        a1 = fmaf(rA, bits2f((unsigned short)uA[1]),
             fmaf(rB, bits2f((unsigned short)uB[1]),
             fmaf(rC, bits2f((unsigned short)uC[1]),
             fmaf(rD, bits2f((unsigned short)uD[1]), a1))));
        a2 = fmaf(rA, bits2f((unsigned short)uA[2]),
             fmaf(rB, bits2f((unsigned short)uB[2]),
             fmaf(rC, bits2f((unsigned short)uC[2]),
             fmaf(rD, bits2f((unsigned short)uD[2]), a2))));
        a3 = fmaf(rA, bits2f((unsigned short)uA[3]),
             fmaf(rB, bits2f((unsigned short)uB[3]),
             fmaf(rC, bits2f((unsigned short)uC[3]),
             fmaf(rD, bits2f((unsigned short)uD[3]), a3))));
        a4 = fmaf(rA, bits2f((unsigned short)uA[4]),
             fmaf(rB, bits2f((unsigned short)uB[4]),
             fmaf(rC, bits2f((unsigned short)uC[4]),
             fmaf(rD, bits2f((unsigned short)uD[4]), a4))));
        a5 = fmaf(rA, bits2f((unsigned short)uA[5]),
             fmaf(rB, bits2f((unsigned short)uB[5]),
             fmaf(rC, bits2f((unsigned short)uC[5]),
             fmaf(rD, bits2f((unsigned short)uD[5]), a5))));
        a6 = fmaf(rA, bits2f((unsigned short)uA[6]),
             fmaf(rB, bits2f((unsigned short)uB[6]),
             fmaf(rC, bits2f((unsigned short)uC[6]),
             fmaf(rD, bits2f((unsigned short)uD[6]), a6))));
        a7 = fmaf(rA, bits2f((unsigned short)uA[7]),
             fmaf(rB, bits2f((unsigned short)uB[7]),
             fmaf(rC, bits2f((unsigned short)uC[7]),
             fmaf(rD, bits2f((unsigned short)uD[7]), a7))));
    }
    for (; j + 2 <= hi; j += 2){
        int s = csr_src[j+half];
        float r = rs_out[s];
        short8 u = *reinterpret_cast<const short8*>(hn + (size_t)s*HD + l2*8);
        a0 = fmaf(r, bits2f((unsigned short)u[0]), a0);
        a1 = fmaf(r, bits2f((unsigned short)u[1]), a1);
        a2 = fmaf(r, bits2f((unsigned short)u[2]), a2);
        a3 = fmaf(r, bits2f((unsigned short)u[3]), a3);
        a4 = fmaf(r, bits2f((unsigned short)u[4]), a4);
        a5 = fmaf(r, bits2f((unsigned short)u[5]), a5);
        a6 = fmaf(r, bits2f((unsigned short)u[6]), a6);
        a7 = fmaf(r, bits2f((unsigned short)u[7]), a7);
    }
    if (j < hi && half == 0){
        int s = csr_src[j];
        float r = rs_out[s];
        short8 u = *reinterpret_cast<const short8*>(hn + (size_t)s*HD + l2*8);
        a0 = fmaf(r, bits2f((unsigned short)u[0]), a0);
        a1 = fmaf(r, bits2f((unsigned short)u[1]), a1);
        a2 = fmaf(r, bits2f((unsigned short)u[2]), a2);
        a3 = fmaf(r, bits2f((unsigned short)u[3]), a3);
        a4 = fmaf(r, bits2f((unsigned short)u[4]), a4);
        a5 = fmaf(r, bits2f((unsigned short)u[5]), a5);
        a6 = fmaf(r, bits2f((unsigned short)u[6]), a6);
        a7 = fmaf(r, bits2f((unsigned short)u[7]), a7);
    }
    // exchange: send the 4 channels the partner owns, receive my 4
    float send0 = half ? a0 : a4;
    float send1 = half ? a1 : a5;
    float send2 = half ? a2 : a6;
    float send3 = half ? a3 : a7;
    float recv0 = __shfl_xor(send0, 32);
    float recv1 = __shfl_xor(send1, 32);
    float recv2 = __shfl_xor(send2, 32);
    float recv3 = __shfl_xor(send3, 32);
    float tot0 = (half ? a4 : a0) + recv0;
    float tot1 = (half ? a5 : a1) + recv1;
    float tot2 = (half ? a6 : a2) + recv2;
    float tot3 = (half ? a7 : a3) + recv3;
    int db = dcode[5], fg = dcode[2];
    float rsn = rs_in[n];
    int c = l2*8 + half*4;
    float v0 = fmaxf(fmaf(tot0, rsn, ldf3(b_conv, c+0, db)), 0.f);
    float v1 = fmaxf(fmaf(tot1, rsn, ldf3(b_conv, c+1, db)), 0.f);
    float v2 = fmaxf(fmaf(tot2, rsn, ldf3(b_conv, c+2, db)), 0.f);
    float v3 = fmaxf(fmaf(tot3, rsn, ldf3(b_conv, c+3, db)), 0.f);
    float4 fv; fv.x = v0; fv.y = v1; fv.z = v2; fv.w = v3;
    *(float4*)(hr + (size_t)n*HD + c) = fv;
    float g = v0*ldf3(w_gate, c+0, fg) + v1*ldf3(w_gate, c+1, fg)
            + v2*ldf3(w_gate, c+2, fg) + v3*ldf3(w_gate, c+3, fg);
    #pragma unroll
    for (int off = 32; off; off >>= 1) g += __shfl_down(g, off);
    if (lane == 0) gate[n] = g + ldf3(b_gate, 0, db);
}

// fused softmax + attention pool: 8 parts per graph (512 blocks), NO fences.
__global__ __launch_bounds__(256) void k_softhg(const float* __restrict__ gate,
                                                const float* __restrict__ hr,
                                                const int* __restrict__ gstart,
                                                const int* __restrict__ gend,
                                                float* __restrict__ hg,
                                                float* __restrict__ out_att){
    int g = blockIdx.x >> 3, part = blockIdx.x & 7;
    int t = threadIdx.x, lane = t & 63, wid = t >> 6;
    int lo = gstart[g], hi = gend[g], len = hi - lo;
    if (len <= 0) return;
    __shared__ float red[4];
    // --- segment max ---
    float m = -INFINITY;
    for (int n = lo + t; n < hi; n += 256) m = fmaxf(m, gate[n]);
    #pragma unroll
    for (int off = 32; off; off >>= 1) m = fmaxf(m, __shfl_xor(m, off));
    if (lane == 0) red[wid] = m;
    __syncthreads();
    m = fmaxf(fmaxf(red[0], red[1]), fmaxf(red[2], red[3]));
    __syncthreads();
    // --- segment sum of exp ---
    float s = 0.f;
    for (int n = lo + t; n < hi; n += 256) s += expf(gate[n] - m);
    #pragma unroll
    for (int off = 32; off; off >>= 1) s += __shfl_xor(s, off);
    if (lane == 0) red[wid] = s;
    __syncthreads();
    s = red[0] + red[1] + red[2] + red[3];
    float inv = 1.f / s;
    // --- this part's node slice ---
    int chunk = (len + 7) >> 3;
    int plo = lo + part*chunk, phi = min(plo + chunk, hi);
    if (plo >= phi) return;
    for (int n = plo + t; n < phi; n += 256)
        out_att[n] = expf(gate[n] - m) * inv;
    float a0 = 0.f, a1 = 0.f, a2 = 0.f, a3 = 0.f;
    int r = plo;
    for (; r + 4 <= phi; r += 4){
        float w0 = expf(gate[r+0] - m) * inv;
        float w1 = expf(gate[r+1] - m) * inv;
        float w2 = expf(gate[r+2] - m) * inv;
        float w3 = expf(gate[r+3] - m) * inv;
        a0 = fmaf(w0, hr[(size_t)(r+0)*HD + t], a0);
        a1 = fmaf(w1, hr[(size_t)(r+1)*HD + t], a1);
        a2 = fmaf(w2, hr[(size_t)(r+2)*HD + t], a2);
        a3 = fmaf(w3, hr[(size_t)(r+3)*HD + t], a3);
    }
    for (; r < phi; r++)
        a0 = fmaf(expf(gate[r] - m) * inv, hr[(size_t)r*HD + t], a0);
    atomicAdd(&hg[g*HD + t], (a0 + a1) + (a2 + a3));
}

// classifier: one block per graph (round-0 proven)
__global__ __launch_bounds__(256) void k_cls(const float* __restrict__ hg,
                                             const void* __restrict__ W1,
                                             const void* __restrict__ b1,
                                             const void* __restrict__ W2,
                                             const void* __restrict__ b2,
                                             const int* __restrict__ dcode,
                                             float* __restrict__ out0,
                                             float* __restrict__ out_hg){
    int f1 = dcode[3], f2 = dcode[4], db = dcode[5];
    int g = blockIdx.x, tid = threadIdx.x;
    __shared__ float hs[256];
    float hv = hg[g*HD + tid];
    hs[tid] = hv;
    out_hg[g*HD + tid] = hv;
    __syncthreads();
    float acc = ldf3(b1, tid, db);
    if (f1 == 1){
        const bf16* w = (const bf16*)W1;
        for (int k = 0; k < HD; k++) acc += hs[k]*b2f(w[(size_t)k*HD + tid]);
    } else if (f1 == 2){
        const __half* w = (const __half*)W1;
        for (int k = 0; k < HD; k++) acc += hs[k]*__half2float(w[(size_t)k*HD + tid]);
    } else {
        const float* w = (const float*)W1;
        for (int k = 0; k < HD; k++) acc += hs[k]*w[(size_t)k*HD + tid];
    }
    float p0 = acc * ldf3(W2, tid*CC + 0, f2);
    float p1 = acc * ldf3(W2, tid*CC + 1, f2);
    __shared__ float r0[256], r1[256];
    r0[tid] = p0; r1[tid] = p1; __syncthreads();
    for (int s = 128; s; s >>= 1){
        if (tid < s){ r0[tid] += r0[tid+s]; r1[tid] += r1[tid+s]; }
        __syncthreads();
    }
    if (tid == 0){
        out0[g*CC+0] = 1.f/(1.f + expf(-(r0[0] + ldf3(b2, 0, db))));
        out0[g*CC+1] = 1.f/(1.f + expf(-(r1[0] + ldf3(b2, 1, db))));
    }
}

extern "C" void kernel_launch(void* const* d_in, const int* in_sizes, int n_in,
                              void* d_out, int out_size, void* d_ws, size_t ws_size,
                              hipStream_t stream) {
    const void* h      = d_in[0];
    const void* src_r  = d_in[1];
    const void* dst_r  = d_in[2];
    const void* gid_r  = d_in[3];
    const void* W_conv = d_in[4];
    const void* b_conv = d_in[5];
    const void* w_gate = d_in[6];
    const void* b_gate = d_in[7];
    const void* W1     = d_in[8];
    const void* b1     = d_in[9];
    const void* W2     = d_in[10];
    const void* b2     = d_in[11];

    float* out     = (float*)d_out;      // fp32 output (established R10)
    float* out0    = out;                // [G,C]
    float* out_att = out + GG*CC;        // [N]
    float* out_hg  = out + GG*CC + NN;   // [G,H]

    char* w = (char*)d_ws;
    float* hr   = (float*)w;  w += (size_t)NN*HD*sizeof(float);
    bf16*  hn   = (bf16*)w;   w += (size_t)NN*HD*sizeof(bf16);
    bf16*  Wb   = (bf16*)w;   w += (size_t)IND*HD*sizeof(bf16);
    float* rs_o = (float*)w;  w += (size_t)NN*sizeof(float);
    float* rs_i = (float*)w;  w += (size_t)NN*sizeof(float);
    float* gate = (float*)w;  w += (size_t)NN*sizeof(float);
    int* gstart = (int*)w;    w += GG*sizeof(int);
    int* gend   = (int*)w;    w += GG*sizeof(int);
    int* dcode  = (int*)w;    w += 8*sizeof(int);
    int* icode  = (int*)w;    w += 8*sizeof(int);
    int* gid_i  = (int*)w;    w += (size_t)NN*sizeof(int);
    int* cnt_in = (int*)w;    w += (size_t)NN*sizeof(int);
    float* hg   = (float*)w;  w += (size_t)GG*HD*sizeof(float);   // zeroed
    int* rowst  = (int*)w;    w += (size_t)(NN+1)*sizeof(int);
    int* csr    = (int*)w;    w += (size_t)EE*sizeof(int);
    int* pout   = (int*)w;    w += (size_t)HRB*NN*sizeof(int);
    int* pin    = (int*)w;    w += (size_t)HRB*NN*sizeof(int);

    // detection + W transpose + hg zeroing
    k_detect<<<DETB + ZBLK, 256, 0, stream>>>(src_r, dst_r, gid_r,
                                     (const unsigned short*)h, (const unsigned short*)W_conv,
                                     (const unsigned short*)w_gate, (const unsigned short*)W1,
                                     (const unsigned short*)W2, (const unsigned short*)b_conv,
                                     icode, dcode, (int*)hg, Wb);

    // GEMM (coalesced epilogue) + LDS histograms, one launch (overlap)
    k_prepgemm<<<GEMMB + HRB*4, 256, 0, stream>>>(h, Wb, src_r, dst_r,
                                                  icode, dcode, pout, pin, hn);

    k_red<<<(NN+255)/256, 256, 0, stream>>>(gid_r, icode, pout, pin,
                                            rs_o, rs_i, cnt_in, gid_i);

    k_scan<<<1, 1024, 0, stream>>>(cnt_in, gid_i, rowst, gstart, gend);

    k_fill<<<HRB*2, 256, 0, stream>>>(src_r, dst_r, icode, rowst, pin, csr);

    k_gather<<<(NN+3)/4, 256, 0, stream>>>(hn, rs_o, rs_i, rowst, csr,
                                           b_conv, w_gate, b_gate, dcode, hr, gate);

    k_softhg<<<GG*8, 256, 0, stream>>>(gate, hr, gstart, gend, hg, out_att);

    k_cls<<<GG, 256, 0, stream>>>(hg, W1, b1, W2, b2, dcode, out0, out_hg);
}

// Round 17
// 222.973 us; speedup vs baseline: 1.0209x; 1.0016x over previous
//
#include <hip/hip_runtime.h>
#include <hip/hip_bf16.h>
#include <hip/hip_fp16.h>
#include <math.h>

#define NN 20000
#define EE 320000
#define GG 64
#define IND 256
#define HD 256
#define CC 2

#define HRB 32           // edge ranges for histogram/fill
#define EPB (EE/HRB)     // 10000 edges per range
#define NH  (NN/2)       // node half size (LDS histogram fits 40KB)

typedef __hip_bfloat16 bf16;
typedef __attribute__((ext_vector_type(8))) short short8;
typedef __attribute__((ext_vector_type(4))) float f32x4;

__device__ __forceinline__ float b2f(bf16 x){ return __bfloat162float(x); }
__device__ __forceinline__ float bits2f(unsigned short b){
    union{ float f; unsigned u; } v; v.u = ((unsigned)b) << 16; return v.f;
}
__device__ __forceinline__ short f2bs(float x){
    union{ bf16 b; short s; } u; u.b = __float2bfloat16(x); return u.s;
}
// float load by code: 0=fp32, 1=bf16, 2=fp16
__device__ __forceinline__ float ldf3(const void* p, size_t i, int c){
    if (c == 1) return b2f(((const bf16*)p)[i]);
    if (c == 2) return __half2float(((const __half*)p)[i]);
    return ((const float*)p)[i];
}
__device__ __forceinline__ int idec(const void* p, int i, int c){
    if (c == 1) return (int)(((const long long*)p)[i]);
    if (c == 2) return (int)(((const float*)p)[i]);
    if (c == 3) return (int)__half2float(((const __half*)p)[i]);
    return ((const int*)p)[i];
}
// wave-parallel (64-lane) float-dtype detect; call with full wave, t = lane.
__device__ __forceinline__ int wdetect_wave(const unsigned short* p, int t){
    unsigned u = p[2*t];
    int e8 = (u >> 7) & 0xFF;
    int e5 = (u >> 10) & 0x1F;
    int nz = __popcll(__ballot(u != 0));
    int cb = __popcll(__ballot(e8 >= 100 && e8 <= 141));
    int cf = __popcll(__ballot(e5 >= 4 && e5 <= 22));
    return (nz < 8) ? 0 : (cb >= 60) ? 1 : ((cf >= 60) ? 2 : 0);
}

// ---- detection (lane-parallel) + W transpose + hg zeroing ----
#define ZBLK 8
#define DETB (9 + IND)
__global__ __launch_bounds__(256) void k_detect(const void* src, const void* dst,
                         const void* gid,
                         const unsigned short* h, const unsigned short* Wc,
                         const unsigned short* wg, const unsigned short* W1,
                         const unsigned short* W2, const unsigned short* bc,
                         int* icode, int* dcode, int* zero_base,
                         bf16* __restrict__ Wb){
    int blk = blockIdx.x;
    int t = threadIdx.x;
    if (blk < 3){
        if (t >= 64) return;
        const void* buf = (blk == 0) ? src : (blk == 1) ? dst : gid;
        int n     = (blk == 2) ? NN : EE;
        int bound = (blk == 2) ? GG : NN;
        long long v64 = ((const long long*)buf)[n/8 + t];
        unsigned long long bad64 = __ballot(v64 < 0 || v64 >= (long long)bound);
        int v32 = ((const int*)buf)[n/4 + t];
        unsigned long long bad32 = __ballot(v32 < 0 || v32 >= bound);
        float f32v = __uint_as_float(((const unsigned*)buf)[n/4 + t]);
        unsigned long long badf32 = __ballot(!(f32v >= 0.f && f32v < (float)bound));
        float f16v = __half2float(((const __half*)buf)[n/2 + t]);
        unsigned long long badf16 = __ballot(!(f16v >= 0.f && f16v < (float)bound));
        if (t == 0)
            icode[blk] = (bad64 == 0ull) ? 1 : ((bad32 == 0ull) ? 0 :
                         ((badf32 == 0ull) ? 2 : ((badf16 == 0ull) ? 3 : 0)));
    } else if (blk < 9){
        if (t >= 64) return;
        int b = blk - 3;
        const unsigned short* p = b==0?h:b==1?Wc:b==2?wg:b==3?W1:b==4?W2:bc;
        int code = wdetect_wave(p, t);
        if (t == 0) dcode[b] = code;
    } else if (blk < DETB){
        // W_conv[IN][HD] -> Wb[n][k] bf16 (fragment-friendly transpose)
        int k = blk - 9;
        __shared__ int scode;
        if (t < 64){
            int code = wdetect_wave(Wc, t);
            if (t == 0) scode = code;
        }
        __syncthreads();
        int c = scode;
        Wb[(size_t)t*IND + k] = __float2bfloat16(ldf3(Wc, (size_t)k*HD + t, c));
    } else {
        int idx = (blk - DETB)*256 + t;
        const int total = GG*HD;   // hg only (all other buffers written in full)
        for (int i = idx; i < total; i += ZBLK*256) zero_base[i] = 0;
    }
}

// fused MFMA GEMM + LDS-privatized degree histograms (NO global atomics).
// blocks [0, GEMMB): hn[32 rows] = h @ W_conv, coalesced LDS-staged stores.
// blocks [GEMMB, GEMMB+HRB*4): histogram. hb=(blk-GEMMB): hr=hb>>2,
//   role=(hb>>1)&1 (0:src->pout, 1:dst->pin), half=hb&1 (node range half).
// Hist blocks overlap with the GEMM's memory phase (R10/R12-proven; moving
// them earlier (R11), into a cooperative mid-kernel (R13), or splitting by
// node-quarter (R15) all regressed).
#define GEMMB (NN/32)
__global__ __launch_bounds__(256) void k_prepgemm(const void* __restrict__ h,
                                                  const bf16* __restrict__ Wb,
                                                  const void* __restrict__ src_r,
                                                  const void* __restrict__ dst_r,
                                                  const int* __restrict__ icode,
                                                  const int* __restrict__ dcode,
                                                  int* __restrict__ pout,
                                                  int* __restrict__ pin,
                                                  bf16* __restrict__ hn){
    __shared__ int shm[NH];    // 40KB: histogram, or (aliased) epilogue tile
    int blk = blockIdx.x;
    int tid = threadIdx.x;
    if (blk >= GEMMB){
        int hb = blk - GEMMB;
        int hr = hb >> 2, role = (hb >> 1) & 1, half = hb & 1;
        for (int i = tid; i < NH; i += 256) shm[i] = 0;
        __syncthreads();
        const void* arr = role ? dst_r : src_r;
        int code = icode[role];
        int base = hr*EPB;
        for (int e = base + tid; e < base + EPB; e += 256){
            int v = idec(arr, e, code);
            int vh = v - half*NH;
            if ((unsigned)vh < NH) atomicAdd(&shm[vh], 1);
        }
        __syncthreads();
        int* dst_part = (role ? pin : pout) + (size_t)hr*NN + half*NH;
        for (int i = tid; i < NH; i += 256) dst_part[i] = shm[i];
        return;
    }
    unsigned short* tile = (unsigned short*)shm;   // 32*260*2B = 16.6KB <= 40KB
    int fh = dcode[0];
    int wave = tid >> 6, lane = tid & 63;
    int q = lane >> 4, mr = lane & 15;
    int row0 = blk * 32;
    int ncol0 = wave * 64;
    f32x4 acc[2][4] = {};
    const float* hf = (const float*)h;
    #pragma unroll
    for (int k0 = 0; k0 < IND; k0 += 32){
        short8 a[2], b[4];
        if (fh == 0){
            #pragma unroll
            for (int mi = 0; mi < 2; mi++){
                int r = row0 + mi*16 + mr;
                const float4* p = (const float4*)(hf + (size_t)r*IND + k0 + q*8);
                float4 v0 = p[0], v1 = p[1];
                a[mi][0] = f2bs(v0.x); a[mi][1] = f2bs(v0.y);
                a[mi][2] = f2bs(v0.z); a[mi][3] = f2bs(v0.w);
                a[mi][4] = f2bs(v1.x); a[mi][5] = f2bs(v1.y);
                a[mi][6] = f2bs(v1.z); a[mi][7] = f2bs(v1.w);
            }
        } else {
            #pragma unroll
            for (int mi = 0; mi < 2; mi++){
                int r = row0 + mi*16 + mr;
                #pragma unroll
                for (int j = 0; j < 8; j++)
                    a[mi][j] = f2bs(ldf3(h, (size_t)r*IND + k0 + q*8 + j, fh));
            }
        }
        #pragma unroll
        for (int ni = 0; ni < 4; ni++)
            b[ni] = *reinterpret_cast<const short8*>(
                        Wb + (size_t)(ncol0 + ni*16 + mr)*IND + k0 + q*8);
        #pragma unroll
        for (int mi = 0; mi < 2; mi++)
            #pragma unroll
            for (int ni = 0; ni < 4; ni++)
                acc[mi][ni] = __builtin_amdgcn_mfma_f32_16x16x32_bf16(
                                  a[mi], b[ni], acc[mi][ni], 0, 0, 0);
    }
    #pragma unroll
    for (int mi = 0; mi < 2; mi++){
        int rowb = mi*16 + q*4;
        #pragma unroll
        for (int r = 0; r < 4; r++){
            int row = rowb + r;
            #pragma unroll
            for (int ni = 0; ni < 4; ni++)
                tile[row*260 + ncol0 + ni*16 + mr] =
                    (unsigned short)f2bs(acc[mi][ni][r]);
        }
    }
    __syncthreads();
    #pragma unroll
    for (int p = 0; p < 4; p++){
        int s = p*256 + tid;
        int row = s >> 5;
        int c8 = (s & 31) * 8;
        short8 v = *reinterpret_cast<const short8*>(&tile[row*260 + c8]);
        *reinterpret_cast<short8*>(hn + (size_t)(row0 + row)*HD + c8) = v;
    }
}

// per-node reduce: sum pout -> rs_o; exclusive-prefix pin in place ->
// per-range row offsets; totals -> cnt_in, rs_i; decode gid.
__global__ __launch_bounds__(256) void k_red(const void* __restrict__ gid_r,
                                             const int* __restrict__ icode,
                                             int* __restrict__ pout,
                                             int* __restrict__ pin,
                                             float* __restrict__ rs_o,
                                             float* __restrict__ rs_i,
                                             int* __restrict__ cnt_in,
                                             int* __restrict__ gid_i){
    int n = blockIdx.x*256 + threadIdx.x;
    if (n >= NN) return;
    int so = 0;
    #pragma unroll 8
    for (int hr = 0; hr < HRB; hr++) so += pout[(size_t)hr*NN + n];
    rs_o[n] = rsqrtf(fmaxf((float)so, 1.f));
    int pre = 0;
    #pragma unroll 8
    for (int hr = 0; hr < HRB; hr++){
        int v = pin[(size_t)hr*NN + n];
        pin[(size_t)hr*NN + n] = pre;
        pre += v;
    }
    cnt_in[n] = pre;
    rs_i[n] = rsqrtf(fmaxf((float)pre, 1.f));
    gid_i[n] = idec(gid_r, n, icode[2]);
}

// single-block (1024 threads): prefix scan of cnt_in -> rowst + graph ranges
__global__ __launch_bounds__(1024) void k_scan(const int* __restrict__ cnt_in,
                                               const int* __restrict__ gid,
                                               int* __restrict__ row_start,
                                               int* gstart, int* gend){
    int t = threadIdx.x;
    __shared__ int part[1024];
    const int per = (NN + 1023)/1024;
    int lo = t*per, hi = min(lo+per, NN);
    int s = 0;
    for (int i = lo; i < hi; i++) s += cnt_in[i];
    part[t] = s; __syncthreads();
    for (int off = 1; off < 1024; off <<= 1){
        int v = (t >= off) ? part[t-off] : 0;
        __syncthreads();
        part[t] += v;
        __syncthreads();
    }
    int base = part[t] - s;
    for (int i = lo; i < hi; i++){ row_start[i] = base; base += cnt_in[i]; }
    if (t == 1023) row_start[NN] = part[1023];
    __shared__ int ls[GG+1];
    if (t <= GG){
        int a = 0, b = NN;
        while (a < b){
            int mid = (a + b) >> 1;
            if (gid[mid] < t) a = mid + 1; else b = mid;
        }
        ls[t] = a;
    }
    __syncthreads();
    if (t < GG){ gstart[t] = ls[t]; gend[t] = ls[t+1]; }
}

// atomic-free CSR fill: blk -> (hr = blk>>1, half = blk&1). Re-streams range
// hr's edges; slot = rowst[d] + pin_prefix[hr][d] + LDS local rank.
__global__ __launch_bounds__(256) void k_fill(const void* src_r, const void* dst_r,
                       const int* __restrict__ icode,
                       const int* __restrict__ row_start,
                       const int* __restrict__ pin,
                       int* __restrict__ csr_src){
    __shared__ int lr[NH];
    int blk = blockIdx.x, t = threadIdx.x;
    int hr = blk >> 1, half = blk & 1;
    for (int i = t; i < NH; i += 256) lr[i] = 0;
    __syncthreads();
    int c0 = icode[0], c1 = icode[1];
    int base = hr*EPB;
    const int* pre = pin + (size_t)hr*NN;
    for (int e = base + t; e < base + EPB; e += 256){
        int s = idec(src_r, e, c0);
        int d = idec(dst_r, e, c1);
        if ((unsigned)s >= NN || (unsigned)d >= NN) continue;
        int dh = d - half*NH;
        if ((unsigned)dh < NH){
            int r = atomicAdd(&lr[dh], 1);
            csr_src[row_start[d] + pre[d] + r] = s;
        }
    }
}

// fused gather + epilogue: one wave per dst node.
// Half-wave pairing: lanes l and l+32 read DIFFERENT edges with 16B short8
// loads. rs_out[src] applied per-edge via fma.
__global__ __launch_bounds__(256) void k_gather(const bf16* __restrict__ hn,
                                                const float* __restrict__ rs_out,
                                                const float* __restrict__ rs_in,
                                                const int* __restrict__ row_start,
                                                const int* __restrict__ csr_src,
                                                const void* __restrict__ b_conv,
                                                const void* __restrict__ w_gate,
                                                const void* __restrict__ b_gate,
                                                const int* __restrict__ dcode,
                                                float* __restrict__ hr,
                                                float* __restrict__ gate){
    int wave = threadIdx.x >> 6, lane = threadIdx.x & 63;
    int n = blockIdx.x*4 + wave;
    if (n >= NN) return;
    int lo = row_start[n], hi = row_start[n+1];
    int half = lane >> 5, l2 = lane & 31;
    float a0=0.f,a1=0.f,a2=0.f,a3=0.f,a4=0.f,a5=0.f,a6=0.f,a7=0.f;
    int j = lo;
    for (; j + 8 <= hi; j += 8){
        int sA = csr_src[j+0+half], sB = csr_src[j+2+half];
        int sC = csr_src[j+4+half], sD = csr_src[j+6+half];
        float rA = rs_out[sA], rB = rs_out[sB], rC = rs_out[sC], rD = rs_out[sD];
        short8 uA = *reinterpret_cast<const short8*>(hn + (size_t)sA*HD + l2*8);
        short8 uB = *reinterpret_cast<const short8*>(hn + (size_t)sB*HD + l2*8);
        short8 uC = *reinterpret_cast<const short8*>(hn + (size_t)sC*HD + l2*8);
        short8 uD = *reinterpret_cast<const short8*>(hn + (size_t)sD*HD + l2*8);
        a0 = fmaf(rA, bits2f((unsigned short)uA[0]),
             fmaf(rB, bits2f((unsigned short)uB[0]),
             fmaf(rC, bits2f((unsigned short)uC[0]),
             fmaf(rD, bits2f((unsigned short)uD[0]), a0))));
        a1 = fmaf(rA, bits2f((unsigned short)uA[1]),
             fmaf(rB, bits2f((unsigned short)uB[1]),
             fmaf(rC, bits2f((unsigned short)uC[1]),
             fmaf(rD, bits2f((unsigned short)uD[1]), a1))));
        a2 = fmaf(rA, bits2f((unsigned short)uA[2]),
             fmaf(rB, bits2f((unsigned short)uB[2]),
             fmaf(rC, bits2f((unsigned short)uC[2]),
             fmaf(rD, bits2f((unsigned short)uD[2]), a2))));
        a3 = fmaf(rA, bits2f((unsigned short)uA[3]),
             fmaf(rB, bits2f((unsigned short)uB[3]),
             fmaf(rC, bits2f((unsigned short)uC[3]),
             fmaf(rD, bits2f((unsigned short)uD[3]), a3))));
        a4 = fmaf(rA, bits2f((unsigned short)uA[4]),
             fmaf(rB, bits2f((unsigned short)uB[4]),
             fmaf(rC, bits2f((unsigned short)uC[4]),
             fmaf(rD, bits2f((unsigned short)uD[4]), a4))));
        a5 = fmaf(rA, bits2f((unsigned short)uA[5]),
             fmaf(rB, bits2f((unsigned short)uB[5]),
             fmaf(rC, bits2f((unsigned short)uC[5]),
             fmaf(rD, bits2f((unsigned short)uD[5]), a5))));
        a6 = fmaf(rA, bits2f((unsigned short)uA[6]),
             fmaf(rB, bits2f((unsigned short)uB[6]),
             fmaf(rC, bits2f((unsigned short)uC[6]),
             fmaf(rD, bits2f((unsigned short)uD[6]), a6))));
        a7 = fmaf(rA, bits2f((unsigned short)uA[7]),
             fmaf(rB, bits2f((unsigned short)uB[7]),
             fmaf(rC, bits2f((unsigned short)uC[7]),
             fmaf(rD, bits2f((unsigned short)uD[7]), a7))));
    }
    for (; j + 2 <= hi; j += 2){
        int s = csr_src[j+half];
        float r = rs_out[s];
        short8 u = *reinterpret_cast<const short8*>(hn + (size_t)s*HD + l2*8);
        a0 = fmaf(r, bits2f((unsigned short)u[0]), a0);
        a1 = fmaf(r, bits2f((unsigned short)u[1]), a1);
        a2 = fmaf(r, bits2f((unsigned short)u[2]), a2);
        a3 = fmaf(r, bits2f((unsigned short)u[3]), a3);
        a4 = fmaf(r, bits2f((unsigned short)u[4]), a4);
        a5 = fmaf(r, bits2f((unsigned short)u[5]), a5);
        a6 = fmaf(r, bits2f((unsigned short)u[6]), a6);
        a7 = fmaf(r, bits2f((unsigned short)u[7]), a7);
    }
    if (j < hi && half == 0){
        int s = csr_src[j];
        float r = rs_out[s];
        short8 u = *reinterpret_cast<const short8*>(hn + (size_t)s*HD + l2*8);
        a0 = fmaf(r, bits2f((unsigned short)u[0]), a0);
        a1 = fmaf(r, bits2f((unsigned short)u[1]), a1);
        a2 = fmaf(r, bits2f((unsigned short)u[2]), a2);
        a3 = fmaf(r, bits2f((unsigned short)u[3]), a3);
        a4 = fmaf(r, bits2f((unsigned short)u[4]), a4);
        a5 = fmaf(r, bits2f((unsigned short)u[5]), a5);
        a6 = fmaf(r, bits2f((unsigned short)u[6]), a6);
        a7 = fmaf(r, bits2f((unsigned short)u[7]), a7);
    }
    // exchange: send the 4 channels the partner owns, receive my 4
    float send0 = half ? a0 : a4;
    float send1 = half ? a1 : a5;
    float send2 = half ? a2 : a6;
    float send3 = half ? a3 : a7;
    float recv0 = __shfl_xor(send0, 32);
    float recv1 = __shfl_xor(send1, 32);
    float recv2 = __shfl_xor(send2, 32);
    float recv3 = __shfl_xor(send3, 32);
    float tot0 = (half ? a4 : a0) + recv0;
    float tot1 = (half ? a5 : a1) + recv1;
    float tot2 = (half ? a6 : a2) + recv2;
    float tot3 = (half ? a7 : a3) + recv3;
    int db = dcode[5], fg = dcode[2];
    float rsn = rs_in[n];
    int c = l2*8 + half*4;
    float v0 = fmaxf(fmaf(tot0, rsn, ldf3(b_conv, c+0, db)), 0.f);
    float v1 = fmaxf(fmaf(tot1, rsn, ldf3(b_conv, c+1, db)), 0.f);
    float v2 = fmaxf(fmaf(tot2, rsn, ldf3(b_conv, c+2, db)), 0.f);
    float v3 = fmaxf(fmaf(tot3, rsn, ldf3(b_conv, c+3, db)), 0.f);
    float4 fv; fv.x = v0; fv.y = v1; fv.z = v2; fv.w = v3;
    *(float4*)(hr + (size_t)n*HD + c) = fv;
    float g = v0*ldf3(w_gate, c+0, fg) + v1*ldf3(w_gate, c+1, fg)
            + v2*ldf3(w_gate, c+2, fg) + v3*ldf3(w_gate, c+3, fg);
    #pragma unroll
    for (int off = 32; off; off >>= 1) g += __shfl_down(g, off);
    if (lane == 0) gate[n] = g + ldf3(b_gate, 0, db);
}

// fused softmax + attention pool: 8 parts per graph (512 blocks), NO fences.
__global__ __launch_bounds__(256) void k_softhg(const float* __restrict__ gate,
                                                const float* __restrict__ hr,
                                                const int* __restrict__ gstart,
                                                const int* __restrict__ gend,
                                                float* __restrict__ hg,
                                                float* __restrict__ out_att){
    int g = blockIdx.x >> 3, part = blockIdx.x & 7;
    int t = threadIdx.x, lane = t & 63, wid = t >> 6;
    int lo = gstart[g], hi = gend[g], len = hi - lo;
    if (len <= 0) return;
    __shared__ float red[4];
    // --- segment max ---
    float m = -INFINITY;
    for (int n = lo + t; n < hi; n += 256) m = fmaxf(m, gate[n]);
    #pragma unroll
    for (int off = 32; off; off >>= 1) m = fmaxf(m, __shfl_xor(m, off));
    if (lane == 0) red[wid] = m;
    __syncthreads();
    m = fmaxf(fmaxf(red[0], red[1]), fmaxf(red[2], red[3]));
    __syncthreads();
    // --- segment sum of exp ---
    float s = 0.f;
    for (int n = lo + t; n < hi; n += 256) s += expf(gate[n] - m);
    #pragma unroll
    for (int off = 32; off; off >>= 1) s += __shfl_xor(s, off);
    if (lane == 0) red[wid] = s;
    __syncthreads();
    s = red[0] + red[1] + red[2] + red[3];
    float inv = 1.f / s;
    // --- this part's node slice ---
    int chunk = (len + 7) >> 3;
    int plo = lo + part*chunk, phi = min(plo + chunk, hi);
    if (plo >= phi) return;
    for (int n = plo + t; n < phi; n += 256)
        out_att[n] = expf(gate[n] - m) * inv;
    float a0 = 0.f, a1 = 0.f, a2 = 0.f, a3 = 0.f;
    int r = plo;
    for (; r + 4 <= phi; r += 4){
        float w0 = expf(gate[r+0] - m) * inv;
        float w1 = expf(gate[r+1] - m) * inv;
        float w2 = expf(gate[r+2] - m) * inv;
        float w3 = expf(gate[r+3] - m) * inv;
        a0 = fmaf(w0, hr[(size_t)(r+0)*HD + t], a0);
        a1 = fmaf(w1, hr[(size_t)(r+1)*HD + t], a1);
        a2 = fmaf(w2, hr[(size_t)(r+2)*HD + t], a2);
        a3 = fmaf(w3, hr[(size_t)(r+3)*HD + t], a3);
    }
    for (; r < phi; r++)
        a0 = fmaf(expf(gate[r] - m) * inv, hr[(size_t)r*HD + t], a0);
    atomicAdd(&hg[g*HD + t], (a0 + a1) + (a2 + a3));
}

// classifier: one block per graph (round-0 proven)
__global__ __launch_bounds__(256) void k_cls(const float* __restrict__ hg,
                                             const void* __restrict__ W1,
                                             const void* __restrict__ b1,
                                             const void* __restrict__ W2,
                                             const void* __restrict__ b2,
                                             const int* __restrict__ dcode,
                                             float* __restrict__ out0,
                                             float* __restrict__ out_hg){
    int f1 = dcode[3], f2 = dcode[4], db = dcode[5];
    int g = blockIdx.x, tid = threadIdx.x;
    __shared__ float hs[256];
    float hv = hg[g*HD + tid];
    hs[tid] = hv;
    out_hg[g*HD + tid] = hv;
    __syncthreads();
    float acc = ldf3(b1, tid, db);
    if (f1 == 1){
        const bf16* w = (const bf16*)W1;
        for (int k = 0; k < HD; k++) acc += hs[k]*b2f(w[(size_t)k*HD + tid]);
    } else if (f1 == 2){
        const __half* w = (const __half*)W1;
        for (int k = 0; k < HD; k++) acc += hs[k]*__half2float(w[(size_t)k*HD + tid]);
    } else {
        const float* w = (const float*)W1;
        for (int k = 0; k < HD; k++) acc += hs[k]*w[(size_t)k*HD + tid];
    }
    float p0 = acc * ldf3(W2, tid*CC + 0, f2);
    float p1 = acc * ldf3(W2, tid*CC + 1, f2);
    __shared__ float r0[256], r1[256];
    r0[tid] = p0; r1[tid] = p1; __syncthreads();
    for (int s = 128; s; s >>= 1){
        if (tid < s){ r0[tid] += r0[tid+s]; r1[tid] += r1[tid+s]; }
        __syncthreads();
    }
    if (tid == 0){
        out0[g*CC+0] = 1.f/(1.f + expf(-(r0[0] + ldf3(b2, 0, db))));
        out0[g*CC+1] = 1.f/(1.f + expf(-(r1[0] + ldf3(b2, 1, db))));
    }
}

extern "C" void kernel_launch(void* const* d_in, const int* in_sizes, int n_in,
                              void* d_out, int out_size, void* d_ws, size_t ws_size,
                              hipStream_t stream) {
    const void* h      = d_in[0];
    const void* src_r  = d_in[1];
    const void* dst_r  = d_in[2];
    const void* gid_r  = d_in[3];
    const void* W_conv = d_in[4];
    const void* b_conv = d_in[5];
    const void* w_gate = d_in[6];
    const void* b_gate = d_in[7];
    const void* W1     = d_in[8];
    const void* b1     = d_in[9];
    const void* W2     = d_in[10];
    const void* b2     = d_in[11];

    float* out     = (float*)d_out;      // fp32 output (established R10)
    float* out0    = out;                // [G,C]
    float* out_att = out + GG*CC;        // [N]
    float* out_hg  = out + GG*CC + NN;   // [G,H]

    char* w = (char*)d_ws;
    float* hr   = (float*)w;  w += (size_t)NN*HD*sizeof(float);
    bf16*  hn   = (bf16*)w;   w += (size_t)NN*HD*sizeof(bf16);
    bf16*  Wb   = (bf16*)w;   w += (size_t)IND*HD*sizeof(bf16);
    float* rs_o = (float*)w;  w += (size_t)NN*sizeof(float);
    float* rs_i = (float*)w;  w += (size_t)NN*sizeof(float);
    float* gate = (float*)w;  w += (size_t)NN*sizeof(float);
    int* gstart = (int*)w;    w += GG*sizeof(int);
    int* gend   = (int*)w;    w += GG*sizeof(int);
    int* dcode  = (int*)w;    w += 8*sizeof(int);
    int* icode  = (int*)w;    w += 8*sizeof(int);
    int* gid_i  = (int*)w;    w += (size_t)NN*sizeof(int);
    int* cnt_in = (int*)w;    w += (size_t)NN*sizeof(int);
    float* hg   = (float*)w;  w += (size_t)GG*HD*sizeof(float);   // zeroed
    int* rowst  = (int*)w;    w += (size_t)(NN+1)*sizeof(int);
    int* csr    = (int*)w;    w += (size_t)EE*sizeof(int);
    int* pout   = (int*)w;    w += (size_t)HRB*NN*sizeof(int);
    int* pin    = (int*)w;    w += (size_t)HRB*NN*sizeof(int);

    // detection + W transpose + hg zeroing
    k_detect<<<DETB + ZBLK, 256, 0, stream>>>(src_r, dst_r, gid_r,
                                     (const unsigned short*)h, (const unsigned short*)W_conv,
                                     (const unsigned short*)w_gate, (const unsigned short*)W1,
                                     (const unsigned short*)W2, (const unsigned short*)b_conv,
                                     icode, dcode, (int*)hg, Wb);

    // GEMM (coalesced epilogue) + LDS histograms, one launch (overlap)
    k_prepgemm<<<GEMMB + HRB*4, 256, 0, stream>>>(h, Wb, src_r, dst_r,
                                                  icode, dcode, pout, pin, hn);

    k_red<<<(NN+255)/256, 256, 0, stream>>>(gid_r, icode, pout, pin,
                                            rs_o, rs_i, cnt_in, gid_i);

    k_scan<<<1, 1024, 0, stream>>>(cnt_in, gid_i, rowst, gstart, gend);

    k_fill<<<HRB*2, 256, 0, stream>>>(src_r, dst_r, icode, rowst, pin, csr);

    k_gather<<<(NN+3)/4, 256, 0, stream>>>(hn, rs_o, rs_i, rowst, csr,
                                           b_conv, w_gate, b_gate, dcode, hr, gate);

    k_softhg<<<GG*8, 256, 0, stream>>>(gate, hr, gstart, gend, hg, out_att);

    k_cls<<<GG, 256, 0, stream>>>(hg, W1, b1, W2, b2, dcode, out0, out_hg);
}

// Round 19
// 206.031 us; speedup vs baseline: 1.1049x; 1.0822x over previous
//
#include <hip/hip_runtime.h>
#include <hip/hip_bf16.h>
#include <hip/hip_fp16.h>
#include <math.h>

#define NN 20000
#define EE 320000
#define GG 64
#define IND 256
#define HD 256
#define CC 2

#define HRB 32           // edge ranges for histogram/fill
#define EPB (EE/HRB)     // 10000 edges per range
#define NH  (NN/2)       // node half size (LDS histogram fits 40KB)

typedef __hip_bfloat16 bf16;
typedef __attribute__((ext_vector_type(8))) short short8;
typedef __attribute__((ext_vector_type(4))) float f32x4;

__device__ __forceinline__ float b2f(bf16 x){ return __bfloat162float(x); }
__device__ __forceinline__ float bits2f(unsigned short b){
    union{ float f; unsigned u; } v; v.u = ((unsigned)b) << 16; return v.f;
}
__device__ __forceinline__ short f2bs(float x){
    union{ bf16 b; short s; } u; u.b = __float2bfloat16(x); return u.s;
}
// float load by code: 0=fp32, 1=bf16, 2=fp16
__device__ __forceinline__ float ldf3(const void* p, size_t i, int c){
    if (c == 1) return b2f(((const bf16*)p)[i]);
    if (c == 2) return __half2float(((const __half*)p)[i]);
    return ((const float*)p)[i];
}
__device__ __forceinline__ int idec(const void* p, int i, int c){
    if (c == 1) return (int)(((const long long*)p)[i]);
    if (c == 2) return (int)(((const float*)p)[i]);
    if (c == 3) return (int)__half2float(((const __half*)p)[i]);
    return ((const int*)p)[i];
}
// wave-parallel (64-lane) float-dtype detect; call with full wave, t = lane.
__device__ __forceinline__ int wdetect_wave(const unsigned short* p, int t){
    unsigned u = p[2*t];
    int e8 = (u >> 7) & 0xFF;
    int e5 = (u >> 10) & 0x1F;
    int nz = __popcll(__ballot(u != 0));
    int cb = __popcll(__ballot(e8 >= 100 && e8 <= 141));
    int cf = __popcll(__ballot(e5 >= 4 && e5 <= 22));
    return (nz < 8) ? 0 : (cb >= 60) ? 1 : ((cf >= 60) ? 2 : 0);
}

// ---- detection (lane-parallel) + W transpose + hg zeroing ----
#define ZBLK 8
#define DETB (9 + IND)
__global__ __launch_bounds__(256) void k_detect(const void* src, const void* dst,
                         const void* gid,
                         const unsigned short* h, const unsigned short* Wc,
                         const unsigned short* wg, const unsigned short* W1,
                         const unsigned short* W2, const unsigned short* bc,
                         int* icode, int* dcode, int* zero_base,
                         bf16* __restrict__ Wb){
    int blk = blockIdx.x;
    int t = threadIdx.x;
    if (blk < 3){
        if (t >= 64) return;
        const void* buf = (blk == 0) ? src : (blk == 1) ? dst : gid;
        int n     = (blk == 2) ? NN : EE;
        int bound = (blk == 2) ? GG : NN;
        long long v64 = ((const long long*)buf)[n/8 + t];
        unsigned long long bad64 = __ballot(v64 < 0 || v64 >= (long long)bound);
        int v32 = ((const int*)buf)[n/4 + t];
        unsigned long long bad32 = __ballot(v32 < 0 || v32 >= bound);
        float f32v = __uint_as_float(((const unsigned*)buf)[n/4 + t]);
        unsigned long long badf32 = __ballot(!(f32v >= 0.f && f32v < (float)bound));
        float f16v = __half2float(((const __half*)buf)[n/2 + t]);
        unsigned long long badf16 = __ballot(!(f16v >= 0.f && f16v < (float)bound));
        if (t == 0)
            icode[blk] = (bad64 == 0ull) ? 1 : ((bad32 == 0ull) ? 0 :
                         ((badf32 == 0ull) ? 2 : ((badf16 == 0ull) ? 3 : 0)));
    } else if (blk < 9){
        if (t >= 64) return;
        int b = blk - 3;
        const unsigned short* p = b==0?h:b==1?Wc:b==2?wg:b==3?W1:b==4?W2:bc;
        int code = wdetect_wave(p, t);
        if (t == 0) dcode[b] = code;
    } else if (blk < DETB){
        // W_conv[IN][HD] -> Wb[n][k] bf16 (fragment-friendly transpose)
        int k = blk - 9;
        __shared__ int scode;
        if (t < 64){
            int code = wdetect_wave(Wc, t);
            if (t == 0) scode = code;
        }
        __syncthreads();
        int c = scode;
        Wb[(size_t)t*IND + k] = __float2bfloat16(ldf3(Wc, (size_t)k*HD + t, c));
    } else {
        int idx = (blk - DETB)*256 + t;
        const int total = GG*HD;   // hg only (all other buffers written in full)
        for (int i = idx; i < total; i += ZBLK*256) zero_base[i] = 0;
    }
}

// fused MFMA GEMM + LDS-privatized degree histograms (NO global atomics).
// blocks [0, GEMMB): hn[32 rows] = h @ W_conv, coalesced LDS-staged stores.
// blocks [GEMMB, GEMMB+HRB*4): histogram. hb=(blk-GEMMB): hr=hb>>2,
//   role=(hb>>1)&1 (0:src->pout, 1:dst->pin), half=hb&1 (node range half).
// Hist blocks overlap with the GEMM's memory phase (R10/R12-proven; moving
// them earlier (R11), into a cooperative mid-kernel (R13), or splitting by
// node-quarter (R15) all regressed).
#define GEMMB (NN/32)
__global__ __launch_bounds__(256) void k_prepgemm(const void* __restrict__ h,
                                                  const bf16* __restrict__ Wb,
                                                  const void* __restrict__ src_r,
                                                  const void* __restrict__ dst_r,
                                                  const int* __restrict__ icode,
                                                  const int* __restrict__ dcode,
                                                  int* __restrict__ pout,
                                                  int* __restrict__ pin,
                                                  bf16* __restrict__ hn){
    __shared__ int shm[NH];    // 40KB: histogram, or (aliased) epilogue tile
    int blk = blockIdx.x;
    int tid = threadIdx.x;
    if (blk >= GEMMB){
        int hb = blk - GEMMB;
        int hr = hb >> 2, role = (hb >> 1) & 1, half = hb & 1;
        for (int i = tid; i < NH; i += 256) shm[i] = 0;
        __syncthreads();
        const void* arr = role ? dst_r : src_r;
        int code = icode[role];
        int base = hr*EPB;
        for (int e = base + tid; e < base + EPB; e += 256){
            int v = idec(arr, e, code);
            int vh = v - half*NH;
            if ((unsigned)vh < NH) atomicAdd(&shm[vh], 1);
        }
        __syncthreads();
        int* dst_part = (role ? pin : pout) + (size_t)hr*NN + half*NH;
        for (int i = tid; i < NH; i += 256) dst_part[i] = shm[i];
        return;
    }
    unsigned short* tile = (unsigned short*)shm;   // 32*260*2B = 16.6KB <= 40KB
    int fh = dcode[0];
    int wave = tid >> 6, lane = tid & 63;
    int q = lane >> 4, mr = lane & 15;
    int row0 = blk * 32;
    int ncol0 = wave * 64;
    f32x4 acc[2][4] = {};
    const float* hf = (const float*)h;
    #pragma unroll
    for (int k0 = 0; k0 < IND; k0 += 32){
        short8 a[2], b[4];
        if (fh == 0){
            #pragma unroll
            for (int mi = 0; mi < 2; mi++){
                int r = row0 + mi*16 + mr;
                const float4* p = (const float4*)(hf + (size_t)r*IND + k0 + q*8);
                float4 v0 = p[0], v1 = p[1];
                a[mi][0] = f2bs(v0.x); a[mi][1] = f2bs(v0.y);
                a[mi][2] = f2bs(v0.z); a[mi][3] = f2bs(v0.w);
                a[mi][4] = f2bs(v1.x); a[mi][5] = f2bs(v1.y);
                a[mi][6] = f2bs(v1.z); a[mi][7] = f2bs(v1.w);
            }
        } else {
            #pragma unroll
            for (int mi = 0; mi < 2; mi++){
                int r = row0 + mi*16 + mr;
                #pragma unroll
                for (int j = 0; j < 8; j++)
                    a[mi][j] = f2bs(ldf3(h, (size_t)r*IND + k0 + q*8 + j, fh));
            }
        }
        #pragma unroll
        for (int ni = 0; ni < 4; ni++)
            b[ni] = *reinterpret_cast<const short8*>(
                        Wb + (size_t)(ncol0 + ni*16 + mr)*IND + k0 + q*8);
        #pragma unroll
        for (int mi = 0; mi < 2; mi++)
            #pragma unroll
            for (int ni = 0; ni < 4; ni++)
                acc[mi][ni] = __builtin_amdgcn_mfma_f32_16x16x32_bf16(
                                  a[mi], b[ni], acc[mi][ni], 0, 0, 0);
    }
    #pragma unroll
    for (int mi = 0; mi < 2; mi++){
        int rowb = mi*16 + q*4;
        #pragma unroll
        for (int r = 0; r < 4; r++){
            int row = rowb + r;
            #pragma unroll
            for (int ni = 0; ni < 4; ni++)
                tile[row*260 + ncol0 + ni*16 + mr] =
                    (unsigned short)f2bs(acc[mi][ni][r]);
        }
    }
    __syncthreads();
    #pragma unroll
    for (int p = 0; p < 4; p++){
        int s = p*256 + tid;
        int row = s >> 5;
        int c8 = (s & 31) * 8;
        short8 v = *reinterpret_cast<const short8*>(&tile[row*260 + c8]);
        *reinterpret_cast<short8*>(hn + (size_t)(row0 + row)*HD + c8) = v;
    }
}

// per-node reduce: sum pout -> rs_o; exclusive-prefix pin in place ->
// per-range row offsets; totals -> cnt_in, rs_i; decode gid.
__global__ __launch_bounds__(256) void k_red(const void* __restrict__ gid_r,
                                             const int* __restrict__ icode,
                                             int* __restrict__ pout,
                                             int* __restrict__ pin,
                                             float* __restrict__ rs_o,
                                             float* __restrict__ rs_i,
                                             int* __restrict__ cnt_in,
                                             int* __restrict__ gid_i){
    int n = blockIdx.x*256 + threadIdx.x;
    if (n >= NN) return;
    int so = 0;
    #pragma unroll 8
    for (int hr = 0; hr < HRB; hr++) so += pout[(size_t)hr*NN + n];
    rs_o[n] = rsqrtf(fmaxf((float)so, 1.f));
    int pre = 0;
    #pragma unroll 8
    for (int hr = 0; hr < HRB; hr++){
        int v = pin[(size_t)hr*NN + n];
        pin[(size_t)hr*NN + n] = pre;
        pre += v;
    }
    cnt_in[n] = pre;
    rs_i[n] = rsqrtf(fmaxf((float)pre, 1.f));
    gid_i[n] = idec(gid_r, n, icode[2]);
}

// single-block (1024 threads): prefix scan of cnt_in -> rowst + graph ranges.
// int4-vectorized loads/stores: per-thread slice is exactly 20 ints at a
// 16B-aligned offset (t*80B) -> 5x int4 instead of 20 scalar accesses on
// this latency-critical single-CU kernel.
__global__ __launch_bounds__(1024) void k_scan(const int* __restrict__ cnt_in,
                                               const int* __restrict__ gid,
                                               int* __restrict__ row_start,
                                               int* gstart, int* gend){
    int t = threadIdx.x;
    __shared__ int part[1024];
    const int per = 20;              // (NN + 1023)/1024 with NN=20000
    int lo = t*per;
    int4 v0, v1, v2, v3, v4;
    int s = 0;
    if (lo < NN){
        const int4* p4 = (const int4*)(cnt_in + lo);
        v0 = p4[0]; v1 = p4[1]; v2 = p4[2]; v3 = p4[3]; v4 = p4[4];
        s = v0.x+v0.y+v0.z+v0.w + v1.x+v1.y+v1.z+v1.w
          + v2.x+v2.y+v2.z+v2.w + v3.x+v3.y+v3.z+v3.w
          + v4.x+v4.y+v4.z+v4.w;
    }
    part[t] = s; __syncthreads();
    for (int off = 1; off < 1024; off <<= 1){
        int v = (t >= off) ? part[t-off] : 0;
        __syncthreads();
        part[t] += v;
        __syncthreads();
    }
    if (lo < NN){
        int base = part[t] - s;
        int4* q4 = (int4*)(row_start + lo);
        int4 w;
        w.x = base; base += v0.x; w.y = base; base += v0.y;
        w.z = base; base += v0.z; w.w = base; base += v0.w; q4[0] = w;
        w.x = base; base += v1.x; w.y = base; base += v1.y;
        w.z = base; base += v1.z; w.w = base; base += v1.w; q4[1] = w;
        w.x = base; base += v2.x; w.y = base; base += v2.y;
        w.z = base; base += v2.z; w.w = base; base += v2.w; q4[2] = w;
        w.x = base; base += v3.x; w.y = base; base += v3.y;
        w.z = base; base += v3.z; w.w = base; base += v3.w; q4[3] = w;
        w.x = base; base += v4.x; w.y = base; base += v4.y;
        w.z = base; base += v4.z; w.w = base; base += v4.w; q4[4] = w;
    }
    if (t == 1023) row_start[NN] = part[1023];
    __shared__ int ls[GG+1];
    if (t <= GG){
        int a = 0, b = NN;
        while (a < b){
            int mid = (a + b) >> 1;
            if (gid[mid] < t) a = mid + 1; else b = mid;
        }
        ls[t] = a;
    }
    __syncthreads();
    if (t < GG){ gstart[t] = ls[t]; gend[t] = ls[t+1]; }
}

// atomic-free CSR fill: blk -> (hr = blk>>1, half = blk&1). Re-streams range
// hr's edges; slot = rowst[d] + pin_prefix[hr][d] + LDS local rank.
__global__ __launch_bounds__(256) void k_fill(const void* src_r, const void* dst_r,
                       const int* __restrict__ icode,
                       const int* __restrict__ row_start,
                       const int* __restrict__ pin,
                       int* __restrict__ csr_src){
    __shared__ int lr[NH];
    int blk = blockIdx.x, t = threadIdx.x;
    int hr = blk >> 1, half = blk & 1;
    for (int i = t; i < NH; i += 256) lr[i] = 0;
    __syncthreads();
    int c0 = icode[0], c1 = icode[1];
    int base = hr*EPB;
    const int* pre = pin + (size_t)hr*NN;
    for (int e = base + t; e < base + EPB; e += 256){
        int s = idec(src_r, e, c0);
        int d = idec(dst_r, e, c1);
        if ((unsigned)s >= NN || (unsigned)d >= NN) continue;
        int dh = d - half*NH;
        if ((unsigned)dh < NH){
            int r = atomicAdd(&lr[dh], 1);
            csr_src[row_start[d] + pre[d] + r] = s;
        }
    }
}

// fused gather + epilogue: one wave per dst node.
// Half-wave pairing: lanes l and l+32 read DIFFERENT edges with 16B short8
// loads. rs_out[src] applied per-edge via fma.
__global__ __launch_bounds__(256) void k_gather(const bf16* __restrict__ hn,
                                                const float* __restrict__ rs_out,
                                                const float* __restrict__ rs_in,
                                                const int* __restrict__ row_start,
                                                const int* __restrict__ csr_src,
                                                const void* __restrict__ b_conv,
                                                const void* __restrict__ w_gate,
                                                const void* __restrict__ b_gate,
                                                const int* __restrict__ dcode,
                                                float* __restrict__ hr,
                                                float* __restrict__ gate){
    int wave = threadIdx.x >> 6, lane = threadIdx.x & 63;
    int n = blockIdx.x*4 + wave;
    if (n >= NN) return;
    int lo = row_start[n], hi = row_start[n+1];
    int half = lane >> 5, l2 = lane & 31;
    float a0=0.f,a1=0.f,a2=0.f,a3=0.f,a4=0.f,a5=0.f,a6=0.f,a7=0.f;
    int j = lo;
    for (; j + 8 <= hi; j += 8){
        int sA = csr_src[j+0+half], sB = csr_src[j+2+half];
        int sC = csr_src[j+4+half], sD = csr_src[j+6+half];
        float rA = rs_out[sA], rB = rs_out[sB], rC = rs_out[sC], rD = rs_out[sD];
        short8 uA = *reinterpret_cast<const short8*>(hn + (size_t)sA*HD + l2*8);
        short8 uB = *reinterpret_cast<const short8*>(hn + (size_t)sB*HD + l2*8);
        short8 uC = *reinterpret_cast<const short8*>(hn + (size_t)sC*HD + l2*8);
        short8 uD = *reinterpret_cast<const short8*>(hn + (size_t)sD*HD + l2*8);
        a0 = fmaf(rA, bits2f((unsigned short)uA[0]),
             fmaf(rB, bits2f((unsigned short)uB[0]),
             fmaf(rC, bits2f((unsigned short)uC[0]),
             fmaf(rD, bits2f((unsigned short)uD[0]), a0))));
        a1 = fmaf(rA, bits2f((unsigned short)uA[1]),
             fmaf(rB, bits2f((unsigned short)uB[1]),
             fmaf(rC, bits2f((unsigned short)uC[1]),
             fmaf(rD, bits2f((unsigned short)uD[1]), a1))));
        a2 = fmaf(rA, bits2f((unsigned short)uA[2]),
             fmaf(rB, bits2f((unsigned short)uB[2]),
             fmaf(rC, bits2f((unsigned short)uC[2]),
             fmaf(rD, bits2f((unsigned short)uD[2]), a2))));
        a3 = fmaf(rA, bits2f((unsigned short)uA[3]),
             fmaf(rB, bits2f((unsigned short)uB[3]),
             fmaf(rC, bits2f((unsigned short)uC[3]),
             fmaf(rD, bits2f((unsigned short)uD[3]), a3))));
        a4 = fmaf(rA, bits2f((unsigned short)uA[4]),
             fmaf(rB, bits2f((unsigned short)uB[4]),
             fmaf(rC, bits2f((unsigned short)uC[4]),
             fmaf(rD, bits2f((unsigned short)uD[4]), a4))));
        a5 = fmaf(rA, bits2f((unsigned short)uA[5]),
             fmaf(rB, bits2f((unsigned short)uB[5]),
             fmaf(rC, bits2f((unsigned short)uC[5]),
             fmaf(rD, bits2f((unsigned short)uD[5]), a5))));
        a6 = fmaf(rA, bits2f((unsigned short)uA[6]),
             fmaf(rB, bits2f((unsigned short)uB[6]),
             fmaf(rC, bits2f((unsigned short)uC[6]),
             fmaf(rD, bits2f((unsigned short)uD[6]), a6))));
        a7 = fmaf(rA, bits2f((unsigned short)uA[7]),
             fmaf(rB, bits2f((unsigned short)uB[7]),
             fmaf(rC, bits2f((unsigned short)uC[7]),
             fmaf(rD, bits2f((unsigned short)uD[7]), a7))));
    }
    for (; j + 2 <= hi; j += 2){
        int s = csr_src[j+half];
        float r = rs_out[s];
        short8 u = *reinterpret_cast<const short8*>(hn + (size_t)s*HD + l2*8);
        a0 = fmaf(r, bits2f((unsigned short)u[0]), a0);
        a1 = fmaf(r, bits2f((unsigned short)u[1]), a1);
        a2 = fmaf(r, bits2f((unsigned short)u[2]), a2);
        a3 = fmaf(r, bits2f((unsigned short)u[3]), a3);
        a4 = fmaf(r, bits2f((unsigned short)u[4]), a4);
        a5 = fmaf(r, bits2f((unsigned short)u[5]), a5);
        a6 = fmaf(r, bits2f((unsigned short)u[6]), a6);
        a7 = fmaf(r, bits2f((unsigned short)u[7]), a7);
    }
    if (j < hi && half == 0){
        int s = csr_src[j];
        float r = rs_out[s];
        short8 u = *reinterpret_cast<const short8*>(hn + (size_t)s*HD + l2*8);
        a0 = fmaf(r, bits2f((unsigned short)u[0]), a0);
        a1 = fmaf(r, bits2f((unsigned short)u[1]), a1);
        a2 = fmaf(r, bits2f((unsigned short)u[2]), a2);
        a3 = fmaf(r, bits2f((unsigned short)u[3]), a3);
        a4 = fmaf(r, bits2f((unsigned short)u[4]), a4);
        a5 = fmaf(r, bits2f((unsigned short)u[5]), a5);
        a6 = fmaf(r, bits2f((unsigned short)u[6]), a6);
        a7 = fmaf(r, bits2f((unsigned short)u[7]), a7);
    }
    // exchange: send the 4 channels the partner owns, receive my 4
    float send0 = half ? a0 : a4;
    float send1 = half ? a1 : a5;
    float send2 = half ? a2 : a6;
    float send3 = half ? a3 : a7;
    float recv0 = __shfl_xor(send0, 32);
    float recv1 = __shfl_xor(send1, 32);
    float recv2 = __shfl_xor(send2, 32);
    float recv3 = __shfl_xor(send3, 32);
    float tot0 = (half ? a4 : a0) + recv0;
    float tot1 = (half ? a5 : a1) + recv1;
    float tot2 = (half ? a6 : a2) + recv2;
    float tot3 = (half ? a7 : a3) + recv3;
    int db = dcode[5], fg = dcode[2];
    float rsn = rs_in[n];
    int c = l2*8 + half*4;
    float v0 = fmaxf(fmaf(tot0, rsn, ldf3(b_conv, c+0, db)), 0.f);
    float v1 = fmaxf(fmaf(tot1, rsn, ldf3(b_conv, c+1, db)), 0.f);
    float v2 = fmaxf(fmaf(tot2, rsn, ldf3(b_conv, c+2, db)), 0.f);
    float v3 = fmaxf(fmaf(tot3, rsn, ldf3(b_conv, c+3, db)), 0.f);
    float4 fv; fv.x = v0; fv.y = v1; fv.z = v2; fv.w = v3;
    *(float4*)(hr + (size_t)n*HD + c) = fv;
    float g = v0*ldf3(w_gate, c+0, fg) + v1*ldf3(w_gate, c+1, fg)
            + v2*ldf3(w_gate, c+2, fg) + v3*ldf3(w_gate, c+3, fg);
    #pragma unroll
    for (int off = 32; off; off >>= 1) g += __shfl_down(g, off);
    if (lane == 0) gate[n] = g + ldf3(b_gate, 0, db);
}

// fused softmax + attention pool: 8 parts per graph (512 blocks), NO fences.
__global__ __launch_bounds__(256) void k_softhg(const float* __restrict__ gate,
                                                const float* __restrict__ hr,
                                                const int* __restrict__ gstart,
                                                const int* __restrict__ gend,
                                                float* __restrict__ hg,
                                                float* __restrict__ out_att){
    int g = blockIdx.x >> 3, part = blockIdx.x & 7;
    int t = threadIdx.x, lane = t & 63, wid = t >> 6;
    int lo = gstart[g], hi = gend[g], len = hi - lo;
    if (len <= 0) return;
    __shared__ float red[4];
    // --- segment max ---
    float m = -INFINITY;
    for (int n = lo + t; n < hi; n += 256) m = fmaxf(m, gate[n]);
    #pragma unroll
    for (int off = 32; off; off >>= 1) m = fmaxf(m, __shfl_xor(m, off));
    if (lane == 0) red[wid] = m;
    __syncthreads();
    m = fmaxf(fmaxf(red[0], red[1]), fmaxf(red[2], red[3]));
    __syncthreads();
    // --- segment sum of exp ---
    float s = 0.f;
    for (int n = lo + t; n < hi; n += 256) s += expf(gate[n] - m);
    #pragma unroll
    for (int off = 32; off; off >>= 1) s += __shfl_xor(s, off);
    if (lane == 0) red[wid] = s;
    __syncthreads();
    s = red[0] + red[1] + red[2] + red[3];
    float inv = 1.f / s;
    // --- this part's node slice ---
    int chunk = (len + 7) >> 3;
    int plo = lo + part*chunk, phi = min(plo + chunk, hi);
    if (plo >= phi) return;
    for (int n = plo + t; n < phi; n += 256)
        out_att[n] = expf(gate[n] - m) * inv;
    float a0 = 0.f, a1 = 0.f, a2 = 0.f, a3 = 0.f;
    int r = plo;
    for (; r + 4 <= phi; r += 4){
        float w0 = expf(gate[r+0] - m) * inv;
        float w1 = expf(gate[r+1] - m) * inv;
        float w2 = expf(gate[r+2] - m) * inv;
        float w3 = expf(gate[r+3] - m) * inv;
        a0 = fmaf(w0, hr[(size_t)(r+0)*HD + t], a0);
        a1 = fmaf(w1, hr[(size_t)(r+1)*HD + t], a1);
        a2 = fmaf(w2, hr[(size_t)(r+2)*HD + t], a2);
        a3 = fmaf(w3, hr[(size_t)(r+3)*HD + t], a3);
    }
    for (; r < phi; r++)
        a0 = fmaf(expf(gate[r] - m) * inv, hr[(size_t)r*HD + t], a0);
    atomicAdd(&hg[g*HD + t], (a0 + a1) + (a2 + a3));
}

// classifier: one block per graph (round-0 proven)
__global__ __launch_bounds__(256) void k_cls(const float* __restrict__ hg,
                                             const void* __restrict__ W1,
                                             const void* __restrict__ b1,
                                             const void* __restrict__ W2,
                                             const void* __restrict__ b2,
                                             const int* __restrict__ dcode,
                                             float* __restrict__ out0,
                                             float* __restrict__ out_hg){
    int f1 = dcode[3], f2 = dcode[4], db = dcode[5];
    int g = blockIdx.x, tid = threadIdx.x;
    __shared__ float hs[256];
    float hv = hg[g*HD + tid];
    hs[tid] = hv;
    out_hg[g*HD + tid] = hv;
    __syncthreads();
    float acc = ldf3(b1, tid, db);
    if (f1 == 1){
        const bf16* w = (const bf16*)W1;
        for (int k = 0; k < HD; k++) acc += hs[k]*b2f(w[(size_t)k*HD + tid]);
    } else if (f1 == 2){
        const __half* w = (const __half*)W1;
        for (int k = 0; k < HD; k++) acc += hs[k]*__half2float(w[(size_t)k*HD + tid]);
    } else {
        const float* w = (const float*)W1;
        for (int k = 0; k < HD; k++) acc += hs[k]*w[(size_t)k*HD + tid];
    }
    float p0 = acc * ldf3(W2, tid*CC + 0, f2);
    float p1 = acc * ldf3(W2, tid*CC + 1, f2);
    __shared__ float r0[256], r1[256];
    r0[tid] = p0; r1[tid] = p1; __syncthreads();
    for (int s = 128; s; s >>= 1){
        if (tid < s){ r0[tid] += r0[tid+s]; r1[tid] += r1[tid+s]; }
        __syncthreads();
    }
    if (tid == 0){
        out0[g*CC+0] = 1.f/(1.f + expf(-(r0[0] + ldf3(b2, 0, db))));
        out0[g*CC+1] = 1.f/(1.f + expf(-(r1[0] + ldf3(b2, 1, db))));
    }
}

extern "C" void kernel_launch(void* const* d_in, const int* in_sizes, int n_in,
                              void* d_out, int out_size, void* d_ws, size_t ws_size,
                              hipStream_t stream) {
    const void* h      = d_in[0];
    const void* src_r  = d_in[1];
    const void* dst_r  = d_in[2];
    const void* gid_r  = d_in[3];
    const void* W_conv = d_in[4];
    const void* b_conv = d_in[5];
    const void* w_gate = d_in[6];
    const void* b_gate = d_in[7];
    const void* W1     = d_in[8];
    const void* b1     = d_in[9];
    const void* W2     = d_in[10];
    const void* b2     = d_in[11];

    float* out     = (float*)d_out;      // fp32 output (established R10)
    float* out0    = out;                // [G,C]
    float* out_att = out + GG*CC;        // [N]
    float* out_hg  = out + GG*CC + NN;   // [G,H]

    char* w = (char*)d_ws;
    float* hr   = (float*)w;  w += (size_t)NN*HD*sizeof(float);
    bf16*  hn   = (bf16*)w;   w += (size_t)NN*HD*sizeof(bf16);
    bf16*  Wb   = (bf16*)w;   w += (size_t)IND*HD*sizeof(bf16);
    float* rs_o = (float*)w;  w += (size_t)NN*sizeof(float);
    float* rs_i = (float*)w;  w += (size_t)NN*sizeof(float);
    float* gate = (float*)w;  w += (size_t)NN*sizeof(float);
    int* gstart = (int*)w;    w += GG*sizeof(int);
    int* gend   = (int*)w;    w += GG*sizeof(int);
    int* dcode  = (int*)w;    w += 8*sizeof(int);
    int* icode  = (int*)w;    w += 8*sizeof(int);
    int* gid_i  = (int*)w;    w += (size_t)NN*sizeof(int);
    int* cnt_in = (int*)w;    w += (size_t)NN*sizeof(int);
    float* hg   = (float*)w;  w += (size_t)GG*HD*sizeof(float);   // zeroed
    int* rowst  = (int*)w;    w += (size_t)(NN+1)*sizeof(int);
    int* csr    = (int*)w;    w += (size_t)EE*sizeof(int);
    int* pout   = (int*)w;    w += (size_t)HRB*NN*sizeof(int);
    int* pin    = (int*)w;    w += (size_t)HRB*NN*sizeof(int);

    // detection + W transpose + hg zeroing
    k_detect<<<DETB + ZBLK, 256, 0, stream>>>(src_r, dst_r, gid_r,
                                     (const unsigned short*)h, (const unsigned short*)W_conv,
                                     (const unsigned short*)w_gate, (const unsigned short*)W1,
                                     (const unsigned short*)W2, (const unsigned short*)b_conv,
                                     icode, dcode, (int*)hg, Wb);

    // GEMM (coalesced epilogue) + LDS histograms, one launch (overlap)
    k_prepgemm<<<GEMMB + HRB*4, 256, 0, stream>>>(h, Wb, src_r, dst_r,
                                                  icode, dcode, pout, pin, hn);

    k_red<<<(NN+255)/256, 256, 0, stream>>>(gid_r, icode, pout, pin,
                                            rs_o, rs_i, cnt_in, gid_i);

    k_scan<<<1, 1024, 0, stream>>>(cnt_in, gid_i, rowst, gstart, gend);

    k_fill<<<HRB*2, 256, 0, stream>>>(src_r, dst_r, icode, rowst, pin, csr);

    k_gather<<<(NN+3)/4, 256, 0, stream>>>(hn, rs_o, rs_i, rowst, csr,
                                           b_conv, w_gate, b_gate, dcode, hr, gate);

    k_softhg<<<GG*8, 256, 0, stream>>>(gate, hr, gstart, gend, hg, out_att);

    k_cls<<<GG, 256, 0, stream>>>(hg, W1, b1, W2, b2, dcode, out0, out_hg);
}

// Round 20
// 205.619 us; speedup vs baseline: 1.1071x; 1.0020x over previous
//
#include <hip/hip_runtime.h>
#include <hip/hip_bf16.h>
#include <hip/hip_fp16.h>
#include <math.h>

#define NN 20000
#define EE 320000
#define GG 64
#define IND 256
#define HD 256
#define CC 2

#define HRB 32           // edge ranges for histogram/fill
#define EPB (EE/HRB)     // 10000 edges per range
#define NH  (NN/2)       // node half size (LDS histogram fits 40KB)

typedef __hip_bfloat16 bf16;
typedef __attribute__((ext_vector_type(8))) short short8;
typedef __attribute__((ext_vector_type(4))) float f32x4;

__device__ __forceinline__ float b2f(bf16 x){ return __bfloat162float(x); }
__device__ __forceinline__ float bits2f(unsigned short b){
    union{ float f; unsigned u; } v; v.u = ((unsigned)b) << 16; return v.f;
}
__device__ __forceinline__ short f2bs(float x){
    union{ bf16 b; short s; } u; u.b = __float2bfloat16(x); return u.s;
}
// float load by code: 0=fp32, 1=bf16, 2=fp16
__device__ __forceinline__ float ldf3(const void* p, size_t i, int c){
    if (c == 1) return b2f(((const bf16*)p)[i]);
    if (c == 2) return __half2float(((const __half*)p)[i]);
    return ((const float*)p)[i];
}
__device__ __forceinline__ int idec(const void* p, int i, int c){
    if (c == 1) return (int)(((const long long*)p)[i]);
    if (c == 2) return (int)(((const float*)p)[i]);
    if (c == 3) return (int)__half2float(((const __half*)p)[i]);
    return ((const int*)p)[i];
}
// wave-parallel (64-lane) float-dtype detect; call with full wave, t = lane.
__device__ __forceinline__ int wdetect_wave(const unsigned short* p, int t){
    unsigned u = p[2*t];
    int e8 = (u >> 7) & 0xFF;
    int e5 = (u >> 10) & 0x1F;
    int nz = __popcll(__ballot(u != 0));
    int cb = __popcll(__ballot(e8 >= 100 && e8 <= 141));
    int cf = __popcll(__ballot(e5 >= 4 && e5 <= 22));
    return (nz < 8) ? 0 : (cb >= 60) ? 1 : ((cf >= 60) ? 2 : 0);
}

// ---- detection (lane-parallel) + W transpose + hg zeroing ----
#define ZBLK 8
#define DETB (9 + IND)
__global__ __launch_bounds__(256) void k_detect(const void* src, const void* dst,
                         const void* gid,
                         const unsigned short* h, const unsigned short* Wc,
                         const unsigned short* wg, const unsigned short* W1,
                         const unsigned short* W2, const unsigned short* bc,
                         int* icode, int* dcode, int* zero_base,
                         bf16* __restrict__ Wb){
    int blk = blockIdx.x;
    int t = threadIdx.x;
    if (blk < 3){
        if (t >= 64) return;
        const void* buf = (blk == 0) ? src : (blk == 1) ? dst : gid;
        int n     = (blk == 2) ? NN : EE;
        int bound = (blk == 2) ? GG : NN;
        long long v64 = ((const long long*)buf)[n/8 + t];
        unsigned long long bad64 = __ballot(v64 < 0 || v64 >= (long long)bound);
        int v32 = ((const int*)buf)[n/4 + t];
        unsigned long long bad32 = __ballot(v32 < 0 || v32 >= bound);
        float f32v = __uint_as_float(((const unsigned*)buf)[n/4 + t]);
        unsigned long long badf32 = __ballot(!(f32v >= 0.f && f32v < (float)bound));
        float f16v = __half2float(((const __half*)buf)[n/2 + t]);
        unsigned long long badf16 = __ballot(!(f16v >= 0.f && f16v < (float)bound));
        if (t == 0)
            icode[blk] = (bad64 == 0ull) ? 1 : ((bad32 == 0ull) ? 0 :
                         ((badf32 == 0ull) ? 2 : ((badf16 == 0ull) ? 3 : 0)));
    } else if (blk < 9){
        if (t >= 64) return;
        int b = blk - 3;
        const unsigned short* p = b==0?h:b==1?Wc:b==2?wg:b==3?W1:b==4?W2:bc;
        int code = wdetect_wave(p, t);
        if (t == 0) dcode[b] = code;
    } else if (blk < DETB){
        // W_conv[IN][HD] -> Wb[n][k] bf16 (fragment-friendly transpose)
        int k = blk - 9;
        __shared__ int scode;
        if (t < 64){
            int code = wdetect_wave(Wc, t);
            if (t == 0) scode = code;
        }
        __syncthreads();
        int c = scode;
        Wb[(size_t)t*IND + k] = __float2bfloat16(ldf3(Wc, (size_t)k*HD + t, c));
    } else {
        int idx = (blk - DETB)*256 + t;
        const int total = GG*HD;   // hg only (all other buffers written in full)
        for (int i = idx; i < total; i += ZBLK*256) zero_base[i] = 0;
    }
}

// fused MFMA GEMM + LDS-privatized degree histograms (NO global atomics).
// blocks [0, GEMMB): hn[32 rows] = h @ W_conv, coalesced LDS-staged stores.
// blocks [GEMMB, GEMMB+HRB*4): histogram. hb=(blk-GEMMB): hr=hb>>2,
//   role=(hb>>1)&1 (0:src->pout, 1:dst->pin), half=hb&1 (node range half).
// Hist blocks overlap with the GEMM's memory phase (R10/R12-proven; moving
// them earlier (R11), into a cooperative mid-kernel (R13), or splitting by
// node-quarter (R15) all regressed).
#define GEMMB (NN/32)
__global__ __launch_bounds__(256) void k_prepgemm(const void* __restrict__ h,
                                                  const bf16* __restrict__ Wb,
                                                  const void* __restrict__ src_r,
                                                  const void* __restrict__ dst_r,
                                                  const int* __restrict__ icode,
                                                  const int* __restrict__ dcode,
                                                  int* __restrict__ pout,
                                                  int* __restrict__ pin,
                                                  bf16* __restrict__ hn){
    __shared__ int shm[NH];    // 40KB: histogram, or (aliased) epilogue tile
    int blk = blockIdx.x;
    int tid = threadIdx.x;
    if (blk >= GEMMB){
        int hb = blk - GEMMB;
        int hr = hb >> 2, role = (hb >> 1) & 1, half = hb & 1;
        for (int i = tid; i < NH; i += 256) shm[i] = 0;
        __syncthreads();
        const void* arr = role ? dst_r : src_r;
        int code = icode[role];
        int base = hr*EPB;
        for (int e = base + tid; e < base + EPB; e += 256){
            int v = idec(arr, e, code);
            int vh = v - half*NH;
            if ((unsigned)vh < NH) atomicAdd(&shm[vh], 1);
        }
        __syncthreads();
        int* dst_part = (role ? pin : pout) + (size_t)hr*NN + half*NH;
        for (int i = tid; i < NH; i += 256) dst_part[i] = shm[i];
        return;
    }
    unsigned short* tile = (unsigned short*)shm;   // 32*260*2B = 16.6KB <= 40KB
    int fh = dcode[0];
    int wave = tid >> 6, lane = tid & 63;
    int q = lane >> 4, mr = lane & 15;
    int row0 = blk * 32;
    int ncol0 = wave * 64;
    f32x4 acc[2][4] = {};
    const float* hf = (const float*)h;
    #pragma unroll
    for (int k0 = 0; k0 < IND; k0 += 32){
        short8 a[2], b[4];
        if (fh == 0){
            #pragma unroll
            for (int mi = 0; mi < 2; mi++){
                int r = row0 + mi*16 + mr;
                const float4* p = (const float4*)(hf + (size_t)r*IND + k0 + q*8);
                float4 v0 = p[0], v1 = p[1];
                a[mi][0] = f2bs(v0.x); a[mi][1] = f2bs(v0.y);
                a[mi][2] = f2bs(v0.z); a[mi][3] = f2bs(v0.w);
                a[mi][4] = f2bs(v1.x); a[mi][5] = f2bs(v1.y);
                a[mi][6] = f2bs(v1.z); a[mi][7] = f2bs(v1.w);
            }
        } else {
            #pragma unroll
            for (int mi = 0; mi < 2; mi++){
                int r = row0 + mi*16 + mr;
                #pragma unroll
                for (int j = 0; j < 8; j++)
                    a[mi][j] = f2bs(ldf3(h, (size_t)r*IND + k0 + q*8 + j, fh));
            }
        }
        #pragma unroll
        for (int ni = 0; ni < 4; ni++)
            b[ni] = *reinterpret_cast<const short8*>(
                        Wb + (size_t)(ncol0 + ni*16 + mr)*IND + k0 + q*8);
        #pragma unroll
        for (int mi = 0; mi < 2; mi++)
            #pragma unroll
            for (int ni = 0; ni < 4; ni++)
                acc[mi][ni] = __builtin_amdgcn_mfma_f32_16x16x32_bf16(
                                  a[mi], b[ni], acc[mi][ni], 0, 0, 0);
    }
    #pragma unroll
    for (int mi = 0; mi < 2; mi++){
        int rowb = mi*16 + q*4;
        #pragma unroll
        for (int r = 0; r < 4; r++){
            int row = rowb + r;
            #pragma unroll
            for (int ni = 0; ni < 4; ni++)
                tile[row*260 + ncol0 + ni*16 + mr] =
                    (unsigned short)f2bs(acc[mi][ni][r]);
        }
    }
    __syncthreads();
    #pragma unroll
    for (int p = 0; p < 4; p++){
        int s = p*256 + tid;
        int row = s >> 5;
        int c8 = (s & 31) * 8;
        short8 v = *reinterpret_cast<const short8*>(&tile[row*260 + c8]);
        *reinterpret_cast<short8*>(hn + (size_t)(row0 + row)*HD + c8) = v;
    }
}

// per-node reduce: sum pout -> rs_o; exclusive-prefix pin in place ->
// per-range row offsets; totals -> cnt_in, rs_i; decode gid.
__global__ __launch_bounds__(256) void k_red(const void* __restrict__ gid_r,
                                             const int* __restrict__ icode,
                                             int* __restrict__ pout,
                                             int* __restrict__ pin,
                                             float* __restrict__ rs_o,
                                             float* __restrict__ rs_i,
                                             int* __restrict__ cnt_in,
                                             int* __restrict__ gid_i){
    int n = blockIdx.x*256 + threadIdx.x;
    if (n >= NN) return;
    int so = 0;
    #pragma unroll 8
    for (int hr = 0; hr < HRB; hr++) so += pout[(size_t)hr*NN + n];
    rs_o[n] = rsqrtf(fmaxf((float)so, 1.f));
    int pre = 0;
    #pragma unroll 8
    for (int hr = 0; hr < HRB; hr++){
        int v = pin[(size_t)hr*NN + n];
        pin[(size_t)hr*NN + n] = pre;
        pre += v;
    }
    cnt_in[n] = pre;
    rs_i[n] = rsqrtf(fmaxf((float)pre, 1.f));
    gid_i[n] = idec(gid_r, n, icode[2]);
}

// single-block (1024 threads): prefix scan of cnt_in -> rowst + graph ranges.
// int4-vectorized loads/stores: per-thread slice is exactly 20 ints at a
// 16B-aligned offset (t*80B) -> 5x int4 instead of 20 scalar accesses on
// this latency-critical single-CU kernel. (R19: 222.8 -> 206.0 us.)
__global__ __launch_bounds__(1024) void k_scan(const int* __restrict__ cnt_in,
                                               const int* __restrict__ gid,
                                               int* __restrict__ row_start,
                                               int* gstart, int* gend){
    int t = threadIdx.x;
    __shared__ int part[1024];
    const int per = 20;              // (NN + 1023)/1024 with NN=20000
    int lo = t*per;
    int4 v0, v1, v2, v3, v4;
    int s = 0;
    if (lo < NN){
        const int4* p4 = (const int4*)(cnt_in + lo);
        v0 = p4[0]; v1 = p4[1]; v2 = p4[2]; v3 = p4[3]; v4 = p4[4];
        s = v0.x+v0.y+v0.z+v0.w + v1.x+v1.y+v1.z+v1.w
          + v2.x+v2.y+v2.z+v2.w + v3.x+v3.y+v3.z+v3.w
          + v4.x+v4.y+v4.z+v4.w;
    }
    part[t] = s; __syncthreads();
    for (int off = 1; off < 1024; off <<= 1){
        int v = (t >= off) ? part[t-off] : 0;
        __syncthreads();
        part[t] += v;
        __syncthreads();
    }
    if (lo < NN){
        int base = part[t] - s;
        int4* q4 = (int4*)(row_start + lo);
        int4 w;
        w.x = base; base += v0.x; w.y = base; base += v0.y;
        w.z = base; base += v0.z; w.w = base; base += v0.w; q4[0] = w;
        w.x = base; base += v1.x; w.y = base; base += v1.y;
        w.z = base; base += v1.z; w.w = base; base += v1.w; q4[1] = w;
        w.x = base; base += v2.x; w.y = base; base += v2.y;
        w.z = base; base += v2.z; w.w = base; base += v2.w; q4[2] = w;
        w.x = base; base += v3.x; w.y = base; base += v3.y;
        w.z = base; base += v3.z; w.w = base; base += v3.w; q4[3] = w;
        w.x = base; base += v4.x; w.y = base; base += v4.y;
        w.z = base; base += v4.z; w.w = base; base += v4.w; q4[4] = w;
    }
    if (t == 1023) row_start[NN] = part[1023];
    __shared__ int ls[GG+1];
    if (t <= GG){
        int a = 0, b = NN;
        while (a < b){
            int mid = (a + b) >> 1;
            if (gid[mid] < t) a = mid + 1; else b = mid;
        }
        ls[t] = a;
    }
    __syncthreads();
    if (t < GG){ gstart[t] = ls[t]; gend[t] = ls[t+1]; }
}

// atomic-free CSR fill: blk -> (hr = blk>>1, half = blk&1). Re-streams range
// hr's edges; slot = rowst[d] + pin_prefix[hr][d] + LDS local rank.
__global__ __launch_bounds__(256) void k_fill(const void* src_r, const void* dst_r,
                       const int* __restrict__ icode,
                       const int* __restrict__ row_start,
                       const int* __restrict__ pin,
                       int* __restrict__ csr_src){
    __shared__ int lr[NH];
    int blk = blockIdx.x, t = threadIdx.x;
    int hr = blk >> 1, half = blk & 1;
    for (int i = t; i < NH; i += 256) lr[i] = 0;
    __syncthreads();
    int c0 = icode[0], c1 = icode[1];
    int base = hr*EPB;
    const int* pre = pin + (size_t)hr*NN;
    for (int e = base + t; e < base + EPB; e += 256){
        int s = idec(src_r, e, c0);
        int d = idec(dst_r, e, c1);
        if ((unsigned)s >= NN || (unsigned)d >= NN) continue;
        int dh = d - half*NH;
        if ((unsigned)dh < NH){
            int r = atomicAdd(&lr[dh], 1);
            csr_src[row_start[d] + pre[d] + r] = s;
        }
    }
}

// fused gather + epilogue: one wave per dst node.
// Half-wave pairing: lanes l and l+32 read DIFFERENT edges with 16B short8
// loads. rs_out[src] applied per-edge via fma.
__global__ __launch_bounds__(256) void k_gather(const bf16* __restrict__ hn,
                                                const float* __restrict__ rs_out,
                                                const float* __restrict__ rs_in,
                                                const int* __restrict__ row_start,
                                                const int* __restrict__ csr_src,
                                                const void* __restrict__ b_conv,
                                                const void* __restrict__ w_gate,
                                                const void* __restrict__ b_gate,
                                                const int* __restrict__ dcode,
                                                float* __restrict__ hr,
                                                float* __restrict__ gate){
    int wave = threadIdx.x >> 6, lane = threadIdx.x & 63;
    int n = blockIdx.x*4 + wave;
    if (n >= NN) return;
    int lo = row_start[n], hi = row_start[n+1];
    int half = lane >> 5, l2 = lane & 31;
    float a0=0.f,a1=0.f,a2=0.f,a3=0.f,a4=0.f,a5=0.f,a6=0.f,a7=0.f;
    int j = lo;
    for (; j + 8 <= hi; j += 8){
        int sA = csr_src[j+0+half], sB = csr_src[j+2+half];
        int sC = csr_src[j+4+half], sD = csr_src[j+6+half];
        float rA = rs_out[sA], rB = rs_out[sB], rC = rs_out[sC], rD = rs_out[sD];
        short8 uA = *reinterpret_cast<const short8*>(hn + (size_t)sA*HD + l2*8);
        short8 uB = *reinterpret_cast<const short8*>(hn + (size_t)sB*HD + l2*8);
        short8 uC = *reinterpret_cast<const short8*>(hn + (size_t)sC*HD + l2*8);
        short8 uD = *reinterpret_cast<const short8*>(hn + (size_t)sD*HD + l2*8);
        a0 = fmaf(rA, bits2f((unsigned short)uA[0]),
             fmaf(rB, bits2f((unsigned short)uB[0]),
             fmaf(rC, bits2f((unsigned short)uC[0]),
             fmaf(rD, bits2f((unsigned short)uD[0]), a0))));
        a1 = fmaf(rA, bits2f((unsigned short)uA[1]),
             fmaf(rB, bits2f((unsigned short)uB[1]),
             fmaf(rC, bits2f((unsigned short)uC[1]),
             fmaf(rD, bits2f((unsigned short)uD[1]), a1))));
        a2 = fmaf(rA, bits2f((unsigned short)uA[2]),
             fmaf(rB, bits2f((unsigned short)uB[2]),
             fmaf(rC, bits2f((unsigned short)uC[2]),
             fmaf(rD, bits2f((unsigned short)uD[2]), a2))));
        a3 = fmaf(rA, bits2f((unsigned short)uA[3]),
             fmaf(rB, bits2f((unsigned short)uB[3]),
             fmaf(rC, bits2f((unsigned short)uC[3]),
             fmaf(rD, bits2f((unsigned short)uD[3]), a3))));
        a4 = fmaf(rA, bits2f((unsigned short)uA[4]),
             fmaf(rB, bits2f((unsigned short)uB[4]),
             fmaf(rC, bits2f((unsigned short)uC[4]),
             fmaf(rD, bits2f((unsigned short)uD[4]), a4))));
        a5 = fmaf(rA, bits2f((unsigned short)uA[5]),
             fmaf(rB, bits2f((unsigned short)uB[5]),
             fmaf(rC, bits2f((unsigned short)uC[5]),
             fmaf(rD, bits2f((unsigned short)uD[5]), a5))));
        a6 = fmaf(rA, bits2f((unsigned short)uA[6]),
             fmaf(rB, bits2f((unsigned short)uB[6]),
             fmaf(rC, bits2f((unsigned short)uC[6]),
             fmaf(rD, bits2f((unsigned short)uD[6]), a6))));
        a7 = fmaf(rA, bits2f((unsigned short)uA[7]),
             fmaf(rB, bits2f((unsigned short)uB[7]),
             fmaf(rC, bits2f((unsigned short)uC[7]),
             fmaf(rD, bits2f((unsigned short)uD[7]), a7))));
    }
    for (; j + 2 <= hi; j += 2){
        int s = csr_src[j+half];
        float r = rs_out[s];
        short8 u = *reinterpret_cast<const short8*>(hn + (size_t)s*HD + l2*8);
        a0 = fmaf(r, bits2f((unsigned short)u[0]), a0);
        a1 = fmaf(r, bits2f((unsigned short)u[1]), a1);
        a2 = fmaf(r, bits2f((unsigned short)u[2]), a2);
        a3 = fmaf(r, bits2f((unsigned short)u[3]), a3);
        a4 = fmaf(r, bits2f((unsigned short)u[4]), a4);
        a5 = fmaf(r, bits2f((unsigned short)u[5]), a5);
        a6 = fmaf(r, bits2f((unsigned short)u[6]), a6);
        a7 = fmaf(r, bits2f((unsigned short)u[7]), a7);
    }
    if (j < hi && half == 0){
        int s = csr_src[j];
        float r = rs_out[s];
        short8 u = *reinterpret_cast<const short8*>(hn + (size_t)s*HD + l2*8);
        a0 = fmaf(r, bits2f((unsigned short)u[0]), a0);
        a1 = fmaf(r, bits2f((unsigned short)u[1]), a1);
        a2 = fmaf(r, bits2f((unsigned short)u[2]), a2);
        a3 = fmaf(r, bits2f((unsigned short)u[3]), a3);
        a4 = fmaf(r, bits2f((unsigned short)u[4]), a4);
        a5 = fmaf(r, bits2f((unsigned short)u[5]), a5);
        a6 = fmaf(r, bits2f((unsigned short)u[6]), a6);
        a7 = fmaf(r, bits2f((unsigned short)u[7]), a7);
    }
    // exchange: send the 4 channels the partner owns, receive my 4
    float send0 = half ? a0 : a4;
    float send1 = half ? a1 : a5;
    float send2 = half ? a2 : a6;
    float send3 = half ? a3 : a7;
    float recv0 = __shfl_xor(send0, 32);
    float recv1 = __shfl_xor(send1, 32);
    float recv2 = __shfl_xor(send2, 32);
    float recv3 = __shfl_xor(send3, 32);
    float tot0 = (half ? a4 : a0) + recv0;
    float tot1 = (half ? a5 : a1) + recv1;
    float tot2 = (half ? a6 : a2) + recv2;
    float tot3 = (half ? a7 : a3) + recv3;
    int db = dcode[5], fg = dcode[2];
    float rsn = rs_in[n];
    int c = l2*8 + half*4;
    float v0 = fmaxf(fmaf(tot0, rsn, ldf3(b_conv, c+0, db)), 0.f);
    float v1 = fmaxf(fmaf(tot1, rsn, ldf3(b_conv, c+1, db)), 0.f);
    float v2 = fmaxf(fmaf(tot2, rsn, ldf3(b_conv, c+2, db)), 0.f);
    float v3 = fmaxf(fmaf(tot3, rsn, ldf3(b_conv, c+3, db)), 0.f);
    float4 fv; fv.x = v0; fv.y = v1; fv.z = v2; fv.w = v3;
    *(float4*)(hr + (size_t)n*HD + c) = fv;
    float g = v0*ldf3(w_gate, c+0, fg) + v1*ldf3(w_gate, c+1, fg)
            + v2*ldf3(w_gate, c+2, fg) + v3*ldf3(w_gate, c+3, fg);
    #pragma unroll
    for (int off = 32; off; off >>= 1) g += __shfl_down(g, off);
    if (lane == 0) gate[n] = g + ldf3(b_gate, 0, db);
}

// fused softmax + attention pool: 8 parts per graph (512 blocks), NO fences.
__global__ __launch_bounds__(256) void k_softhg(const float* __restrict__ gate,
                                                const float* __restrict__ hr,
                                                const int* __restrict__ gstart,
                                                const int* __restrict__ gend,
                                                float* __restrict__ hg,
                                                float* __restrict__ out_att){
    int g = blockIdx.x >> 3, part = blockIdx.x & 7;
    int t = threadIdx.x, lane = t & 63, wid = t >> 6;
    int lo = gstart[g], hi = gend[g], len = hi - lo;
    if (len <= 0) return;
    __shared__ float red[4];
    // --- segment max ---
    float m = -INFINITY;
    for (int n = lo + t; n < hi; n += 256) m = fmaxf(m, gate[n]);
    #pragma unroll
    for (int off = 32; off; off >>= 1) m = fmaxf(m, __shfl_xor(m, off));
    if (lane == 0) red[wid] = m;
    __syncthreads();
    m = fmaxf(fmaxf(red[0], red[1]), fmaxf(red[2], red[3]));
    __syncthreads();
    // --- segment sum of exp ---
    float s = 0.f;
    for (int n = lo + t; n < hi; n += 256) s += expf(gate[n] - m);
    #pragma unroll
    for (int off = 32; off; off >>= 1) s += __shfl_xor(s, off);
    if (lane == 0) red[wid] = s;
    __syncthreads();
    s = red[0] + red[1] + red[2] + red[3];
    float inv = 1.f / s;
    // --- this part's node slice ---
    int chunk = (len + 7) >> 3;
    int plo = lo + part*chunk, phi = min(plo + chunk, hi);
    if (plo >= phi) return;
    for (int n = plo + t; n < phi; n += 256)
        out_att[n] = expf(gate[n] - m) * inv;
    float a0 = 0.f, a1 = 0.f, a2 = 0.f, a3 = 0.f;
    int r = plo;
    for (; r + 4 <= phi; r += 4){
        float w0 = expf(gate[r+0] - m) * inv;
        float w1 = expf(gate[r+1] - m) * inv;
        float w2 = expf(gate[r+2] - m) * inv;
        float w3 = expf(gate[r+3] - m) * inv;
        a0 = fmaf(w0, hr[(size_t)(r+0)*HD + t], a0);
        a1 = fmaf(w1, hr[(size_t)(r+1)*HD + t], a1);
        a2 = fmaf(w2, hr[(size_t)(r+2)*HD + t], a2);
        a3 = fmaf(w3, hr[(size_t)(r+3)*HD + t], a3);
    }
    for (; r < phi; r++)
        a0 = fmaf(expf(gate[r] - m) * inv, hr[(size_t)r*HD + t], a0);
    atomicAdd(&hg[g*HD + t], (a0 + a1) + (a2 + a3));
}

// classifier: one block per graph (round-0 proven)
__global__ __launch_bounds__(256) void k_cls(const float* __restrict__ hg,
                                             const void* __restrict__ W1,
                                             const void* __restrict__ b1,
                                             const void* __restrict__ W2,
                                             const void* __restrict__ b2,
                                             const int* __restrict__ dcode,
                                             float* __restrict__ out0,
                                             float* __restrict__ out_hg){
    int f1 = dcode[3], f2 = dcode[4], db = dcode[5];
    int g = blockIdx.x, tid = threadIdx.x;
    __shared__ float hs[256];
    float hv = hg[g*HD + tid];
    hs[tid] = hv;
    out_hg[g*HD + tid] = hv;
    __syncthreads();
    float acc = ldf3(b1, tid, db);
    if (f1 == 1){
        const bf16* w = (const bf16*)W1;
        for (int k = 0; k < HD; k++) acc += hs[k]*b2f(w[(size_t)k*HD + tid]);
    } else if (f1 == 2){
        const __half* w = (const __half*)W1;
        for (int k = 0; k < HD; k++) acc += hs[k]*__half2float(w[(size_t)k*HD + tid]);
    } else {
        const float* w = (const float*)W1;
        for (int k = 0; k < HD; k++) acc += hs[k]*w[(size_t)k*HD + tid];
    }
    float p0 = acc * ldf3(W2, tid*CC + 0, f2);
    float p1 = acc * ldf3(W2, tid*CC + 1, f2);
    __shared__ float r0[256], r1[256];
    r0[tid] = p0; r1[tid] = p1; __syncthreads();
    for (int s = 128; s; s >>= 1){
        if (tid < s){ r0[tid] += r0[tid+s]; r1[tid] += r1[tid+s]; }
        __syncthreads();
    }
    if (tid == 0){
        out0[g*CC+0] = 1.f/(1.f + expf(-(r0[0] + ldf3(b2, 0, db))));
        out0[g*CC+1] = 1.f/(1.f + expf(-(r1[0] + ldf3(b2, 1, db))));
    }
}

extern "C" void kernel_launch(void* const* d_in, const int* in_sizes, int n_in,
                              void* d_out, int out_size, void* d_ws, size_t ws_size,
                              hipStream_t stream) {
    const void* h      = d_in[0];
    const void* src_r  = d_in[1];
    const void* dst_r  = d_in[2];
    const void* gid_r  = d_in[3];
    const void* W_conv = d_in[4];
    const void* b_conv = d_in[5];
    const void* w_gate = d_in[6];
    const void* b_gate = d_in[7];
    const void* W1     = d_in[8];
    const void* b1     = d_in[9];
    const void* W2     = d_in[10];
    const void* b2     = d_in[11];

    float* out     = (float*)d_out;      // fp32 output (established R10)
    float* out0    = out;                // [G,C]
    float* out_att = out + GG*CC;        // [N]
    float* out_hg  = out + GG*CC + NN;   // [G,H]

    char* w = (char*)d_ws;
    float* hr   = (float*)w;  w += (size_t)NN*HD*sizeof(float);
    bf16*  hn   = (bf16*)w;   w += (size_t)NN*HD*sizeof(bf16);
    bf16*  Wb   = (bf16*)w;   w += (size_t)IND*HD*sizeof(bf16);
    float* rs_o = (float*)w;  w += (size_t)NN*sizeof(float);
    float* rs_i = (float*)w;  w += (size_t)NN*sizeof(float);
    float* gate = (float*)w;  w += (size_t)NN*sizeof(float);
    int* gstart = (int*)w;    w += GG*sizeof(int);
    int* gend   = (int*)w;    w += GG*sizeof(int);
    int* dcode  = (int*)w;    w += 8*sizeof(int);
    int* icode  = (int*)w;    w += 8*sizeof(int);
    int* gid_i  = (int*)w;    w += (size_t)NN*sizeof(int);
    int* cnt_in = (int*)w;    w += (size_t)NN*sizeof(int);
    float* hg   = (float*)w;  w += (size_t)GG*HD*sizeof(float);   // zeroed
    int* rowst  = (int*)w;    w += (size_t)(NN+1)*sizeof(int);
    int* csr    = (int*)w;    w += (size_t)EE*sizeof(int);
    int* pout   = (int*)w;    w += (size_t)HRB*NN*sizeof(int);
    int* pin    = (int*)w;    w += (size_t)HRB*NN*sizeof(int);

    // detection + W transpose + hg zeroing
    k_detect<<<DETB + ZBLK, 256, 0, stream>>>(src_r, dst_r, gid_r,
                                     (const unsigned short*)h, (const unsigned short*)W_conv,
                                     (const unsigned short*)w_gate, (const unsigned short*)W1,
                                     (const unsigned short*)W2, (const unsigned short*)b_conv,
                                     icode, dcode, (int*)hg, Wb);

    // GEMM (coalesced epilogue) + LDS histograms, one launch (overlap)
    k_prepgemm<<<GEMMB + HRB*4, 256, 0, stream>>>(h, Wb, src_r, dst_r,
                                                  icode, dcode, pout, pin, hn);

    k_red<<<(NN+255)/256, 256, 0, stream>>>(gid_r, icode, pout, pin,
                                            rs_o, rs_i, cnt_in, gid_i);

    k_scan<<<1, 1024, 0, stream>>>(cnt_in, gid_i, rowst, gstart, gend);

    k_fill<<<HRB*2, 256, 0, stream>>>(src_r, dst_r, icode, rowst, pin, csr);

    k_gather<<<(NN+3)/4, 256, 0, stream>>>(hn, rs_o, rs_i, rowst, csr,
                                           b_conv, w_gate, b_gate, dcode, hr, gate);

    k_softhg<<<GG*8, 256, 0, stream>>>(gate, hr, gstart, gend, hg, out_att);

    k_cls<<<GG, 256, 0, stream>>>(hg, W1, b1, W2, b2, dcode, out0, out_hg);
}

// Round 21
// 204.604 us; speedup vs baseline: 1.1126x; 1.0050x over previous
//
#include <hip/hip_runtime.h>
#include <hip/hip_bf16.h>
#include <hip/hip_fp16.h>
#include <math.h>

#define NN 20000
#define EE 320000
#define GG 64
#define IND 256
#define HD 256
#define CC 2

#define HRB 32           // edge ranges for histogram/fill
#define EPB (EE/HRB)     // 10000 edges per range
#define NH  (NN/2)       // node half size (LDS histogram fits 40KB)

typedef __hip_bfloat16 bf16;
typedef __attribute__((ext_vector_type(8))) short short8;
typedef __attribute__((ext_vector_type(4))) float f32x4;

__device__ __forceinline__ float b2f(bf16 x){ return __bfloat162float(x); }
__device__ __forceinline__ float bits2f(unsigned short b){
    union{ float f; unsigned u; } v; v.u = ((unsigned)b) << 16; return v.f;
}
__device__ __forceinline__ short f2bs(float x){
    union{ bf16 b; short s; } u; u.b = __float2bfloat16(x); return u.s;
}
// float load by code: 0=fp32, 1=bf16, 2=fp16
__device__ __forceinline__ float ldf3(const void* p, size_t i, int c){
    if (c == 1) return b2f(((const bf16*)p)[i]);
    if (c == 2) return __half2float(((const __half*)p)[i]);
    return ((const float*)p)[i];
}
__device__ __forceinline__ int idec(const void* p, int i, int c){
    if (c == 1) return (int)(((const long long*)p)[i]);
    if (c == 2) return (int)(((const float*)p)[i]);
    if (c == 3) return (int)__half2float(((const __half*)p)[i]);
    return ((const int*)p)[i];
}
// wave-parallel (64-lane) float-dtype detect; call with full wave, t = lane.
__device__ __forceinline__ int wdetect_wave(const unsigned short* p, int t){
    unsigned u = p[2*t];
    int e8 = (u >> 7) & 0xFF;
    int e5 = (u >> 10) & 0x1F;
    int nz = __popcll(__ballot(u != 0));
    int cb = __popcll(__ballot(e8 >= 100 && e8 <= 141));
    int cf = __popcll(__ballot(e5 >= 4 && e5 <= 22));
    return (nz < 8) ? 0 : (cb >= 60) ? 1 : ((cf >= 60) ? 2 : 0);
}

// ---- detection (lane-parallel) + W transpose + hg zeroing ----
#define ZBLK 8
#define DETB (9 + IND)
__global__ __launch_bounds__(256) void k_detect(const void* src, const void* dst,
                         const void* gid,
                         const unsigned short* h, const unsigned short* Wc,
                         const unsigned short* wg, const unsigned short* W1,
                         const unsigned short* W2, const unsigned short* bc,
                         int* icode, int* dcode, int* zero_base,
                         bf16* __restrict__ Wb){
    int blk = blockIdx.x;
    int t = threadIdx.x;
    if (blk < 3){
        if (t >= 64) return;
        const void* buf = (blk == 0) ? src : (blk == 1) ? dst : gid;
        int n     = (blk == 2) ? NN : EE;
        int bound = (blk == 2) ? GG : NN;
        long long v64 = ((const long long*)buf)[n/8 + t];
        unsigned long long bad64 = __ballot(v64 < 0 || v64 >= (long long)bound);
        int v32 = ((const int*)buf)[n/4 + t];
        unsigned long long bad32 = __ballot(v32 < 0 || v32 >= bound);
        float f32v = __uint_as_float(((const unsigned*)buf)[n/4 + t]);
        unsigned long long badf32 = __ballot(!(f32v >= 0.f && f32v < (float)bound));
        float f16v = __half2float(((const __half*)buf)[n/2 + t]);
        unsigned long long badf16 = __ballot(!(f16v >= 0.f && f16v < (float)bound));
        if (t == 0)
            icode[blk] = (bad64 == 0ull) ? 1 : ((bad32 == 0ull) ? 0 :
                         ((badf32 == 0ull) ? 2 : ((badf16 == 0ull) ? 3 : 0)));
    } else if (blk < 9){
        if (t >= 64) return;
        int b = blk - 3;
        const unsigned short* p = b==0?h:b==1?Wc:b==2?wg:b==3?W1:b==4?W2:bc;
        int code = wdetect_wave(p, t);
        if (t == 0) dcode[b] = code;
    } else if (blk < DETB){
        // W_conv[IN][HD] -> Wb[n][k] bf16 (fragment-friendly transpose)
        int k = blk - 9;
        __shared__ int scode;
        if (t < 64){
            int code = wdetect_wave(Wc, t);
            if (t == 0) scode = code;
        }
        __syncthreads();
        int c = scode;
        Wb[(size_t)t*IND + k] = __float2bfloat16(ldf3(Wc, (size_t)k*HD + t, c));
    } else {
        int idx = (blk - DETB)*256 + t;
        const int total = GG*HD;   // hg only (all other buffers written in full)
        for (int i = idx; i < total; i += ZBLK*256) zero_base[i] = 0;
    }
}

// fused MFMA GEMM + LDS-privatized degree histograms (NO global atomics).
// blocks [0, GEMMB): hn[32 rows] = h @ W_conv, coalesced LDS-staged stores.
// blocks [GEMMB, GEMMB+HRB*4): histogram. hb=(blk-GEMMB): hr=hb>>2,
//   role=(hb>>1)&1 (0:src->pout, 1:dst->pin), half=hb&1 (node range half).
// Hist blocks overlap with the GEMM's memory phase (R10/R12-proven; moving
// them earlier (R11), into a cooperative mid-kernel (R13), or splitting by
// node-quarter (R15) all regressed).
#define GEMMB (NN/32)
__global__ __launch_bounds__(256) void k_prepgemm(const void* __restrict__ h,
                                                  const bf16* __restrict__ Wb,
                                                  const void* __restrict__ src_r,
                                                  const void* __restrict__ dst_r,
                                                  const int* __restrict__ icode,
                                                  const int* __restrict__ dcode,
                                                  int* __restrict__ pout,
                                                  int* __restrict__ pin,
                                                  bf16* __restrict__ hn){
    __shared__ int shm[NH];    // 40KB: histogram, or (aliased) epilogue tile
    int blk = blockIdx.x;
    int tid = threadIdx.x;
    if (blk >= GEMMB){
        int hb = blk - GEMMB;
        int hr = hb >> 2, role = (hb >> 1) & 1, half = hb & 1;
        for (int i = tid; i < NH; i += 256) shm[i] = 0;
        __syncthreads();
        const void* arr = role ? dst_r : src_r;
        int code = icode[role];
        int base = hr*EPB;
        for (int e = base + tid; e < base + EPB; e += 256){
            int v = idec(arr, e, code);
            int vh = v - half*NH;
            if ((unsigned)vh < NH) atomicAdd(&shm[vh], 1);
        }
        __syncthreads();
        int* dst_part = (role ? pin : pout) + (size_t)hr*NN + half*NH;
        for (int i = tid; i < NH; i += 256) dst_part[i] = shm[i];
        return;
    }
    unsigned short* tile = (unsigned short*)shm;   // 32*260*2B = 16.6KB <= 40KB
    int fh = dcode[0];
    int wave = tid >> 6, lane = tid & 63;
    int q = lane >> 4, mr = lane & 15;
    int row0 = blk * 32;
    int ncol0 = wave * 64;
    f32x4 acc[2][4] = {};
    const float* hf = (const float*)h;
    #pragma unroll
    for (int k0 = 0; k0 < IND; k0 += 32){
        short8 a[2], b[4];
        if (fh == 0){
            #pragma unroll
            for (int mi = 0; mi < 2; mi++){
                int r = row0 + mi*16 + mr;
                const float4* p = (const float4*)(hf + (size_t)r*IND + k0 + q*8);
                float4 v0 = p[0], v1 = p[1];
                a[mi][0] = f2bs(v0.x); a[mi][1] = f2bs(v0.y);
                a[mi][2] = f2bs(v0.z); a[mi][3] = f2bs(v0.w);
                a[mi][4] = f2bs(v1.x); a[mi][5] = f2bs(v1.y);
                a[mi][6] = f2bs(v1.z); a[mi][7] = f2bs(v1.w);
            }
        } else {
            #pragma unroll
            for (int mi = 0; mi < 2; mi++){
                int r = row0 + mi*16 + mr;
                #pragma unroll
                for (int j = 0; j < 8; j++)
                    a[mi][j] = f2bs(ldf3(h, (size_t)r*IND + k0 + q*8 + j, fh));
            }
        }
        #pragma unroll
        for (int ni = 0; ni < 4; ni++)
            b[ni] = *reinterpret_cast<const short8*>(
                        Wb + (size_t)(ncol0 + ni*16 + mr)*IND + k0 + q*8);
        #pragma unroll
        for (int mi = 0; mi < 2; mi++)
            #pragma unroll
            for (int ni = 0; ni < 4; ni++)
                acc[mi][ni] = __builtin_amdgcn_mfma_f32_16x16x32_bf16(
                                  a[mi], b[ni], acc[mi][ni], 0, 0, 0);
    }
    #pragma unroll
    for (int mi = 0; mi < 2; mi++){
        int rowb = mi*16 + q*4;
        #pragma unroll
        for (int r = 0; r < 4; r++){
            int row = rowb + r;
            #pragma unroll
            for (int ni = 0; ni < 4; ni++)
                tile[row*260 + ncol0 + ni*16 + mr] =
                    (unsigned short)f2bs(acc[mi][ni][r]);
        }
    }
    __syncthreads();
    #pragma unroll
    for (int p = 0; p < 4; p++){
        int s = p*256 + tid;
        int row = s >> 5;
        int c8 = (s & 31) * 8;
        short8 v = *reinterpret_cast<const short8*>(&tile[row*260 + c8]);
        *reinterpret_cast<short8*>(hn + (size_t)(row0 + row)*HD + c8) = v;
    }
}

// per-node reduce: sum pout -> rs_o; exclusive-prefix pin in place ->
// per-range row offsets; totals -> cnt_in, rs_i; decode gid.
__global__ __launch_bounds__(256) void k_red(const void* __restrict__ gid_r,
                                             const int* __restrict__ icode,
                                             int* __restrict__ pout,
                                             int* __restrict__ pin,
                                             float* __restrict__ rs_o,
                                             float* __restrict__ rs_i,
                                             int* __restrict__ cnt_in,
                                             int* __restrict__ gid_i){
    int n = blockIdx.x*256 + threadIdx.x;
    if (n >= NN) return;
    int so = 0;
    #pragma unroll 8
    for (int hr = 0; hr < HRB; hr++) so += pout[(size_t)hr*NN + n];
    rs_o[n] = rsqrtf(fmaxf((float)so, 1.f));
    int pre = 0;
    #pragma unroll 8
    for (int hr = 0; hr < HRB; hr++){
        int v = pin[(size_t)hr*NN + n];
        pin[(size_t)hr*NN + n] = pre;
        pre += v;
    }
    cnt_in[n] = pre;
    rs_i[n] = rsqrtf(fmaxf((float)pre, 1.f));
    gid_i[n] = idec(gid_r, n, icode[2]);
}

// single-block (1024 threads): prefix scan of cnt_in -> rowst + graph ranges.
// int4-vectorized loads/stores: per-thread slice is exactly 20 ints at a
// 16B-aligned offset (t*80B) -> 5x int4 instead of 20 scalar accesses on
// this latency-critical single-CU kernel. (R19/R20: 222.8 -> 205.6-206.0 us.)
__global__ __launch_bounds__(1024) void k_scan(const int* __restrict__ cnt_in,
                                               const int* __restrict__ gid,
                                               int* __restrict__ row_start,
                                               int* gstart, int* gend){
    int t = threadIdx.x;
    __shared__ int part[1024];
    const int per = 20;              // (NN + 1023)/1024 with NN=20000
    int lo = t*per;
    int4 v0, v1, v2, v3, v4;
    int s = 0;
    if (lo < NN){
        const int4* p4 = (const int4*)(cnt_in + lo);
        v0 = p4[0]; v1 = p4[1]; v2 = p4[2]; v3 = p4[3]; v4 = p4[4];
        s = v0.x+v0.y+v0.z+v0.w + v1.x+v1.y+v1.z+v1.w
          + v2.x+v2.y+v2.z+v2.w + v3.x+v3.y+v3.z+v3.w
          + v4.x+v4.y+v4.z+v4.w;
    }
    part[t] = s; __syncthreads();
    for (int off = 1; off < 1024; off <<= 1){
        int v = (t >= off) ? part[t-off] : 0;
        __syncthreads();
        part[t] += v;
        __syncthreads();
    }
    if (lo < NN){
        int base = part[t] - s;
        int4* q4 = (int4*)(row_start + lo);
        int4 w;
        w.x = base; base += v0.x; w.y = base; base += v0.y;
        w.z = base; base += v0.z; w.w = base; base += v0.w; q4[0] = w;
        w.x = base; base += v1.x; w.y = base; base += v1.y;
        w.z = base; base += v1.z; w.w = base; base += v1.w; q4[1] = w;
        w.x = base; base += v2.x; w.y = base; base += v2.y;
        w.z = base; base += v2.z; w.w = base; base += v2.w; q4[2] = w;
        w.x = base; base += v3.x; w.y = base; base += v3.y;
        w.z = base; base += v3.z; w.w = base; base += v3.w; q4[3] = w;
        w.x = base; base += v4.x; w.y = base; base += v4.y;
        w.z = base; base += v4.z; w.w = base; base += v4.w; q4[4] = w;
    }
    if (t == 1023) row_start[NN] = part[1023];
    __shared__ int ls[GG+1];
    if (t <= GG){
        int a = 0, b = NN;
        while (a < b){
            int mid = (a + b) >> 1;
            if (gid[mid] < t) a = mid + 1; else b = mid;
        }
        ls[t] = a;
    }
    __syncthreads();
    if (t < GG){ gstart[t] = ls[t]; gend[t] = ls[t+1]; }
}

// atomic-free CSR fill: blk -> (hr = blk>>1, half = blk&1). Re-streams range
// hr's edges; slot = rowst[d] + pin_prefix[hr][d] + LDS local rank.
__global__ __launch_bounds__(256) void k_fill(const void* src_r, const void* dst_r,
                       const int* __restrict__ icode,
                       const int* __restrict__ row_start,
                       const int* __restrict__ pin,
                       int* __restrict__ csr_src){
    __shared__ int lr[NH];
    int blk = blockIdx.x, t = threadIdx.x;
    int hr = blk >> 1, half = blk & 1;
    for (int i = t; i < NH; i += 256) lr[i] = 0;
    __syncthreads();
    int c0 = icode[0], c1 = icode[1];
    int base = hr*EPB;
    const int* pre = pin + (size_t)hr*NN;
    for (int e = base + t; e < base + EPB; e += 256){
        int s = idec(src_r, e, c0);
        int d = idec(dst_r, e, c1);
        if ((unsigned)s >= NN || (unsigned)d >= NN) continue;
        int dh = d - half*NH;
        if ((unsigned)dh < NH){
            int r = atomicAdd(&lr[dh], 1);
            csr_src[row_start[d] + pre[d] + r] = s;
        }
    }
}

// fused gather + epilogue: one wave per dst node.
// Half-wave pairing: lanes l and l+32 read DIFFERENT edges with 16B short8
// loads. rs_out[src] applied per-edge via fma.
__global__ __launch_bounds__(256) void k_gather(const bf16* __restrict__ hn,
                                                const float* __restrict__ rs_out,
                                                const float* __restrict__ rs_in,
                                                const int* __restrict__ row_start,
                                                const int* __restrict__ csr_src,
                                                const void* __restrict__ b_conv,
                                                const void* __restrict__ w_gate,
                                                const void* __restrict__ b_gate,
                                                const int* __restrict__ dcode,
                                                float* __restrict__ hr,
                                                float* __restrict__ gate){
    int wave = threadIdx.x >> 6, lane = threadIdx.x & 63;
    int n = blockIdx.x*4 + wave;
    if (n >= NN) return;
    int lo = row_start[n], hi = row_start[n+1];
    int half = lane >> 5, l2 = lane & 31;
    float a0=0.f,a1=0.f,a2=0.f,a3=0.f,a4=0.f,a5=0.f,a6=0.f,a7=0.f;
    int j = lo;
    for (; j + 8 <= hi; j += 8){
        int sA = csr_src[j+0+half], sB = csr_src[j+2+half];
        int sC = csr_src[j+4+half], sD = csr_src[j+6+half];
        float rA = rs_out[sA], rB = rs_out[sB], rC = rs_out[sC], rD = rs_out[sD];
        short8 uA = *reinterpret_cast<const short8*>(hn + (size_t)sA*HD + l2*8);
        short8 uB = *reinterpret_cast<const short8*>(hn + (size_t)sB*HD + l2*8);
        short8 uC = *reinterpret_cast<const short8*>(hn + (size_t)sC*HD + l2*8);
        short8 uD = *reinterpret_cast<const short8*>(hn + (size_t)sD*HD + l2*8);
        a0 = fmaf(rA, bits2f((unsigned short)uA[0]),
             fmaf(rB, bits2f((unsigned short)uB[0]),
             fmaf(rC, bits2f((unsigned short)uC[0]),
             fmaf(rD, bits2f((unsigned short)uD[0]), a0))));
        a1 = fmaf(rA, bits2f((unsigned short)uA[1]),
             fmaf(rB, bits2f((unsigned short)uB[1]),
             fmaf(rC, bits2f((unsigned short)uC[1]),
             fmaf(rD, bits2f((unsigned short)uD[1]), a1))));
        a2 = fmaf(rA, bits2f((unsigned short)uA[2]),
             fmaf(rB, bits2f((unsigned short)uB[2]),
             fmaf(rC, bits2f((unsigned short)uC[2]),
             fmaf(rD, bits2f((unsigned short)uD[2]), a2))));
        a3 = fmaf(rA, bits2f((unsigned short)uA[3]),
             fmaf(rB, bits2f((unsigned short)uB[3]),
             fmaf(rC, bits2f((unsigned short)uC[3]),
             fmaf(rD, bits2f((unsigned short)uD[3]), a3))));
        a4 = fmaf(rA, bits2f((unsigned short)uA[4]),
             fmaf(rB, bits2f((unsigned short)uB[4]),
             fmaf(rC, bits2f((unsigned short)uC[4]),
             fmaf(rD, bits2f((unsigned short)uD[4]), a4))));
        a5 = fmaf(rA, bits2f((unsigned short)uA[5]),
             fmaf(rB, bits2f((unsigned short)uB[5]),
             fmaf(rC, bits2f((unsigned short)uC[5]),
             fmaf(rD, bits2f((unsigned short)uD[5]), a5))));
        a6 = fmaf(rA, bits2f((unsigned short)uA[6]),
             fmaf(rB, bits2f((unsigned short)uB[6]),
             fmaf(rC, bits2f((unsigned short)uC[6]),
             fmaf(rD, bits2f((unsigned short)uD[6]), a6))));
        a7 = fmaf(rA, bits2f((unsigned short)uA[7]),
             fmaf(rB, bits2f((unsigned short)uB[7]),
             fmaf(rC, bits2f((unsigned short)uC[7]),
             fmaf(rD, bits2f((unsigned short)uD[7]), a7))));
    }
    for (; j + 2 <= hi; j += 2){
        int s = csr_src[j+half];
        float r = rs_out[s];
        short8 u = *reinterpret_cast<const short8*>(hn + (size_t)s*HD + l2*8);
        a0 = fmaf(r, bits2f((unsigned short)u[0]), a0);
        a1 = fmaf(r, bits2f((unsigned short)u[1]), a1);
        a2 = fmaf(r, bits2f((unsigned short)u[2]), a2);
        a3 = fmaf(r, bits2f((unsigned short)u[3]), a3);
        a4 = fmaf(r, bits2f((unsigned short)u[4]), a4);
        a5 = fmaf(r, bits2f((unsigned short)u[5]), a5);
        a6 = fmaf(r, bits2f((unsigned short)u[6]), a6);
        a7 = fmaf(r, bits2f((unsigned short)u[7]), a7);
    }
    if (j < hi && half == 0){
        int s = csr_src[j];
        float r = rs_out[s];
        short8 u = *reinterpret_cast<const short8*>(hn + (size_t)s*HD + l2*8);
        a0 = fmaf(r, bits2f((unsigned short)u[0]), a0);
        a1 = fmaf(r, bits2f((unsigned short)u[1]), a1);
        a2 = fmaf(r, bits2f((unsigned short)u[2]), a2);
        a3 = fmaf(r, bits2f((unsigned short)u[3]), a3);
        a4 = fmaf(r, bits2f((unsigned short)u[4]), a4);
        a5 = fmaf(r, bits2f((unsigned short)u[5]), a5);
        a6 = fmaf(r, bits2f((unsigned short)u[6]), a6);
        a7 = fmaf(r, bits2f((unsigned short)u[7]), a7);
    }
    // exchange: send the 4 channels the partner owns, receive my 4
    float send0 = half ? a0 : a4;
    float send1 = half ? a1 : a5;
    float send2 = half ? a2 : a6;
    float send3 = half ? a3 : a7;
    float recv0 = __shfl_xor(send0, 32);
    float recv1 = __shfl_xor(send1, 32);
    float recv2 = __shfl_xor(send2, 32);
    float recv3 = __shfl_xor(send3, 32);
    float tot0 = (half ? a4 : a0) + recv0;
    float tot1 = (half ? a5 : a1) + recv1;
    float tot2 = (half ? a6 : a2) + recv2;
    float tot3 = (half ? a7 : a3) + recv3;
    int db = dcode[5], fg = dcode[2];
    float rsn = rs_in[n];
    int c = l2*8 + half*4;
    float v0 = fmaxf(fmaf(tot0, rsn, ldf3(b_conv, c+0, db)), 0.f);
    float v1 = fmaxf(fmaf(tot1, rsn, ldf3(b_conv, c+1, db)), 0.f);
    float v2 = fmaxf(fmaf(tot2, rsn, ldf3(b_conv, c+2, db)), 0.f);
    float v3 = fmaxf(fmaf(tot3, rsn, ldf3(b_conv, c+3, db)), 0.f);
    float4 fv; fv.x = v0; fv.y = v1; fv.z = v2; fv.w = v3;
    *(float4*)(hr + (size_t)n*HD + c) = fv;
    float g = v0*ldf3(w_gate, c+0, fg) + v1*ldf3(w_gate, c+1, fg)
            + v2*ldf3(w_gate, c+2, fg) + v3*ldf3(w_gate, c+3, fg);
    #pragma unroll
    for (int off = 32; off; off >>= 1) g += __shfl_down(g, off);
    if (lane == 0) gate[n] = g + ldf3(b_gate, 0, db);
}

// fused softmax + attention pool: 8 parts per graph (512 blocks), NO fences.
__global__ __launch_bounds__(256) void k_softhg(const float* __restrict__ gate,
                                                const float* __restrict__ hr,
                                                const int* __restrict__ gstart,
                                                const int* __restrict__ gend,
                                                float* __restrict__ hg,
                                                float* __restrict__ out_att){
    int g = blockIdx.x >> 3, part = blockIdx.x & 7;
    int t = threadIdx.x, lane = t & 63, wid = t >> 6;
    int lo = gstart[g], hi = gend[g], len = hi - lo;
    if (len <= 0) return;
    __shared__ float red[4];
    // --- segment max ---
    float m = -INFINITY;
    for (int n = lo + t; n < hi; n += 256) m = fmaxf(m, gate[n]);
    #pragma unroll
    for (int off = 32; off; off >>= 1) m = fmaxf(m, __shfl_xor(m, off));
    if (lane == 0) red[wid] = m;
    __syncthreads();
    m = fmaxf(fmaxf(red[0], red[1]), fmaxf(red[2], red[3]));
    __syncthreads();
    // --- segment sum of exp ---
    float s = 0.f;
    for (int n = lo + t; n < hi; n += 256) s += expf(gate[n] - m);
    #pragma unroll
    for (int off = 32; off; off >>= 1) s += __shfl_xor(s, off);
    if (lane == 0) red[wid] = s;
    __syncthreads();
    s = red[0] + red[1] + red[2] + red[3];
    float inv = 1.f / s;
    // --- this part's node slice ---
    int chunk = (len + 7) >> 3;
    int plo = lo + part*chunk, phi = min(plo + chunk, hi);
    if (plo >= phi) return;
    for (int n = plo + t; n < phi; n += 256)
        out_att[n] = expf(gate[n] - m) * inv;
    float a0 = 0.f, a1 = 0.f, a2 = 0.f, a3 = 0.f;
    int r = plo;
    for (; r + 4 <= phi; r += 4){
        float w0 = expf(gate[r+0] - m) * inv;
        float w1 = expf(gate[r+1] - m) * inv;
        float w2 = expf(gate[r+2] - m) * inv;
        float w3 = expf(gate[r+3] - m) * inv;
        a0 = fmaf(w0, hr[(size_t)(r+0)*HD + t], a0);
        a1 = fmaf(w1, hr[(size_t)(r+1)*HD + t], a1);
        a2 = fmaf(w2, hr[(size_t)(r+2)*HD + t], a2);
        a3 = fmaf(w3, hr[(size_t)(r+3)*HD + t], a3);
    }
    for (; r < phi; r++)
        a0 = fmaf(expf(gate[r] - m) * inv, hr[(size_t)r*HD + t], a0);
    atomicAdd(&hg[g*HD + t], (a0 + a1) + (a2 + a3));
}

// classifier: one block per graph (round-0 proven)
__global__ __launch_bounds__(256) void k_cls(const float* __restrict__ hg,
                                             const void* __restrict__ W1,
                                             const void* __restrict__ b1,
                                             const void* __restrict__ W2,
                                             const void* __restrict__ b2,
                                             const int* __restrict__ dcode,
                                             float* __restrict__ out0,
                                             float* __restrict__ out_hg){
    int f1 = dcode[3], f2 = dcode[4], db = dcode[5];
    int g = blockIdx.x, tid = threadIdx.x;
    __shared__ float hs[256];
    float hv = hg[g*HD + tid];
    hs[tid] = hv;
    out_hg[g*HD + tid] = hv;
    __syncthreads();
    float acc = ldf3(b1, tid, db);
    if (f1 == 1){
        const bf16* w = (const bf16*)W1;
        for (int k = 0; k < HD; k++) acc += hs[k]*b2f(w[(size_t)k*HD + tid]);
    } else if (f1 == 2){
        const __half* w = (const __half*)W1;
        for (int k = 0; k < HD; k++) acc += hs[k]*__half2float(w[(size_t)k*HD + tid]);
    } else {
        const float* w = (const float*)W1;
        for (int k = 0; k < HD; k++) acc += hs[k]*w[(size_t)k*HD + tid];
    }
    float p0 = acc * ldf3(W2, tid*CC + 0, f2);
    float p1 = acc * ldf3(W2, tid*CC + 1, f2);
    __shared__ float r0[256], r1[256];
    r0[tid] = p0; r1[tid] = p1; __syncthreads();
    for (int s = 128; s; s >>= 1){
        if (tid < s){ r0[tid] += r0[tid+s]; r1[tid] += r1[tid+s]; }
        __syncthreads();
    }
    if (tid == 0){
        out0[g*CC+0] = 1.f/(1.f + expf(-(r0[0] + ldf3(b2, 0, db))));
        out0[g*CC+1] = 1.f/(1.f + expf(-(r1[0] + ldf3(b2, 1, db))));
    }
}

extern "C" void kernel_launch(void* const* d_in, const int* in_sizes, int n_in,
                              void* d_out, int out_size, void* d_ws, size_t ws_size,
                              hipStream_t stream) {
    const void* h      = d_in[0];
    const void* src_r  = d_in[1];
    const void* dst_r  = d_in[2];
    const void* gid_r  = d_in[3];
    const void* W_conv = d_in[4];
    const void* b_conv = d_in[5];
    const void* w_gate = d_in[6];
    const void* b_gate = d_in[7];
    const void* W1     = d_in[8];
    const void* b1     = d_in[9];
    const void* W2     = d_in[10];
    const void* b2     = d_in[11];

    float* out     = (float*)d_out;      // fp32 output (established R10)
    float* out0    = out;                // [G,C]
    float* out_att = out + GG*CC;        // [N]
    float* out_hg  = out + GG*CC + NN;   // [G,H]

    char* w = (char*)d_ws;
    float* hr   = (float*)w;  w += (size_t)NN*HD*sizeof(float);
    bf16*  hn   = (bf16*)w;   w += (size_t)NN*HD*sizeof(bf16);
    bf16*  Wb   = (bf16*)w;   w += (size_t)IND*HD*sizeof(bf16);
    float* rs_o = (float*)w;  w += (size_t)NN*sizeof(float);
    float* rs_i = (float*)w;  w += (size_t)NN*sizeof(float);
    float* gate = (float*)w;  w += (size_t)NN*sizeof(float);
    int* gstart = (int*)w;    w += GG*sizeof(int);
    int* gend   = (int*)w;    w += GG*sizeof(int);
    int* dcode  = (int*)w;    w += 8*sizeof(int);
    int* icode  = (int*)w;    w += 8*sizeof(int);
    int* gid_i  = (int*)w;    w += (size_t)NN*sizeof(int);
    int* cnt_in = (int*)w;    w += (size_t)NN*sizeof(int);
    float* hg   = (float*)w;  w += (size_t)GG*HD*sizeof(float);   // zeroed
    int* rowst  = (int*)w;    w += (size_t)(NN+1)*sizeof(int);
    int* csr    = (int*)w;    w += (size_t)EE*sizeof(int);
    int* pout   = (int*)w;    w += (size_t)HRB*NN*sizeof(int);
    int* pin    = (int*)w;    w += (size_t)HRB*NN*sizeof(int);

    // detection + W transpose + hg zeroing
    k_detect<<<DETB + ZBLK, 256, 0, stream>>>(src_r, dst_r, gid_r,
                                     (const unsigned short*)h, (const unsigned short*)W_conv,
                                     (const unsigned short*)w_gate, (const unsigned short*)W1,
                                     (const unsigned short*)W2, (const unsigned short*)b_conv,
                                     icode, dcode, (int*)hg, Wb);

    // GEMM (coalesced epilogue) + LDS histograms, one launch (overlap)
    k_prepgemm<<<GEMMB + HRB*4, 256, 0, stream>>>(h, Wb, src_r, dst_r,
                                                  icode, dcode, pout, pin, hn);

    k_red<<<(NN+255)/256, 256, 0, stream>>>(gid_r, icode, pout, pin,
                                            rs_o, rs_i, cnt_in, gid_i);

    k_scan<<<1, 1024, 0, stream>>>(cnt_in, gid_i, rowst, gstart, gend);

    k_fill<<<HRB*2, 256, 0, stream>>>(src_r, dst_r, icode, rowst, pin, csr);

    k_gather<<<(NN+3)/4, 256, 0, stream>>>(hn, rs_o, rs_i, rowst, csr,
                                           b_conv, w_gate, b_gate, dcode, hr, gate);

    k_softhg<<<GG*8, 256, 0, stream>>>(gate, hr, gstart, gend, hg, out_att);

    k_cls<<<GG, 256, 0, stream>>>(hg, W1, b1, W2, b2, dcode, out0, out_hg);
}